// Round 1
// baseline (1043.589 us; speedup 1.0000x reference)
//
#include <hip/hip_runtime.h>
#include <math.h>

static constexpr int Dh = 128;          // hidden/head dim
static constexpr int NH = 4;            // heads
static constexpr int NB = 16;           // batch
static constexpr int SS = 1024;         // seq len
static constexpr int QKV_LD = 3 * Dh * NH;   // 1536 cols of qkv matrix
static constexpr float NEGF = -1e9f;
static constexpr float SCALE = 0.08838834764831843f;  // 1/sqrt(128)

// ---------------- K1: layernorm stats (one block per batch) ----------------
__global__ __launch_bounds__(256) void ln_stats_kernel(const float* __restrict__ x,
                                                       float* __restrict__ stats) {
    const int b = blockIdx.x;
    const int tid = threadIdx.x;
    const int ND = SS * Dh;  // 131072
    const float4* xb = (const float4*)(x + (size_t)b * ND);
    float s = 0.f, ss = 0.f;
    for (int i = tid; i < ND / 4; i += 256) {
        float4 v = xb[i];
        s  += v.x + v.y + v.z + v.w;
        ss += v.x * v.x + v.y * v.y + v.z * v.z + v.w * v.w;
    }
    __shared__ float r1[256], r2[256];
    r1[tid] = s; r2[tid] = ss;
    __syncthreads();
    for (int off = 128; off > 0; off >>= 1) {
        if (tid < off) { r1[tid] += r1[tid + off]; r2[tid] += r2[tid + off]; }
        __syncthreads();
    }
    if (tid == 0) {
        float mu  = r1[0] / (float)ND;
        float var = r2[0] / (float)ND - mu * mu;
        stats[2 * b]     = mu;
        stats[2 * b + 1] = 1.0f / sqrtf(var + 1e-5f);
    }
}

// ---------------- K2: QKV projection GEMM (LN fused on A-load) ----------------
// C[row=(b,s)][n=(h,e)] = sum_d xn[row][d] * W_in[n][d] + b_in[n]
__global__ __launch_bounds__(256) void qkv_proj_kernel(const float* __restrict__ x,
                                                       const float* __restrict__ w,   // [1536][128]
                                                       const float* __restrict__ bias,// [1536]
                                                       const float* __restrict__ stats,
                                                       float* __restrict__ qkv) {
    __shared__ float As[64][68];  // k-major: As[k][row]
    __shared__ float Bs[64][68];  // k-major: Bs[k][col]
    const int tid = threadIdx.x;
    const int tx = tid & 15, ty = tid >> 4;
    const int row0 = blockIdx.y * 64;
    const int col0 = blockIdx.x * 64;
    const int bb = row0 >> 10;           // 64 | 1024 so tile is within one batch
    const float mu = stats[2 * bb], rstd = stats[2 * bb + 1];
    float acc[4][4] = {};
    for (int kk = 0; kk < 128; kk += 64) {
        #pragma unroll
        for (int p = 0; p < 4; ++p) {
            int slot = tid + p * 256;          // 0..1023 (64 rows x 16 float4)
            int r  = slot >> 4;
            int c4 = (slot & 15) << 2;
            float4 v = *(const float4*)(x + (size_t)(row0 + r) * Dh + kk + c4);
            As[c4 + 0][r] = (v.x - mu) * rstd;
            As[c4 + 1][r] = (v.y - mu) * rstd;
            As[c4 + 2][r] = (v.z - mu) * rstd;
            As[c4 + 3][r] = (v.w - mu) * rstd;
            float4 wv = *(const float4*)(w + (size_t)(col0 + r) * Dh + kk + c4);
            Bs[c4 + 0][r] = wv.x;
            Bs[c4 + 1][r] = wv.y;
            Bs[c4 + 2][r] = wv.z;
            Bs[c4 + 3][r] = wv.w;
        }
        __syncthreads();
        #pragma unroll 8
        for (int k = 0; k < 64; ++k) {
            float4 af = *(const float4*)&As[k][ty << 2];
            float4 bf = *(const float4*)&Bs[k][tx << 2];
            float a[4] = {af.x, af.y, af.z, af.w};
            float b[4] = {bf.x, bf.y, bf.z, bf.w};
            #pragma unroll
            for (int i = 0; i < 4; ++i)
                #pragma unroll
                for (int j = 0; j < 4; ++j)
                    acc[i][j] = fmaf(a[i], b[j], acc[i][j]);
        }
        __syncthreads();
    }
    const int n0 = col0 + (tx << 2);
    float4 bi = *(const float4*)(bias + n0);
    #pragma unroll
    for (int i = 0; i < 4; ++i) {
        int m = row0 + (ty << 2) + i;
        float4 o;
        o.x = acc[i][0] + bi.x;
        o.y = acc[i][1] + bi.y;
        o.z = acc[i][2] + bi.z;
        o.w = acc[i][3] + bi.w;
        *(float4*)(qkv + (size_t)m * QKV_LD + n0) = o;
    }
}

// ---------------- K3: flash attention (per (b,h,32-query tile)) ----------------
__global__ __launch_bounds__(256) void attn_kernel(const float* __restrict__ qkv,
                                                   const int* __restrict__ edge,
                                                   float* __restrict__ ctx) {
    const int qt = blockIdx.x, h = blockIdx.y, b = blockIdx.z;
    const int s0 = qt * 32;
    const int tid = threadIdx.x;
    const int tx = tid & 15, ty = tid >> 4;   // ty in [0,16): 2 rows each; tx: 4 keys / 8 dims

    __shared__ float Qs[128][34];       // d-major Q tile: Qs[d][row]
    __shared__ float KV[128 * 68];      // union: K as [128][68] d-major / V as [64][132] row-major
    __shared__ float Ps[32][68];        // probabilities [row][key]

    const float* qkb = qkv + (size_t)b * SS * QKV_LD + h * 384;

    // load Q tile: 32 rows x 128 d
    #pragma unroll
    for (int p = 0; p < 4; ++p) {
        int slot = tid + p * 256;       // 0..1023 (32 rows x 32 float4)
        int r  = slot >> 5;
        int c4 = (slot & 31) << 2;
        float4 v = *(const float4*)(qkb + (size_t)(s0 + r) * QKV_LD + c4);
        Qs[c4 + 0][r] = v.x;
        Qs[c4 + 1][r] = v.y;
        Qs[c4 + 2][r] = v.z;
        Qs[c4 + 3][r] = v.w;
    }

    float m_[2] = {-INFINITY, -INFINITY};
    float l_[2] = {0.f, 0.f};
    float o_[2][8] = {};

    for (int kt = 0; kt < 16; ++kt) {
        const int t0 = kt * 64;
        // ---- load K tile (d-major) ----
        float* Ks = KV;                 // [128][68]
        #pragma unroll
        for (int p = 0; p < 8; ++p) {
            int slot = tid + p * 256;   // 0..2047 (64 keys x 32 float4)
            int r  = slot >> 5;
            int c4 = (slot & 31) << 2;
            float4 v = *(const float4*)(qkb + (size_t)(t0 + r) * QKV_LD + 128 + c4);
            Ks[(c4 + 0) * 68 + r] = v.x;
            Ks[(c4 + 1) * 68 + r] = v.y;
            Ks[(c4 + 2) * 68 + r] = v.z;
            Ks[(c4 + 3) * 68 + r] = v.w;
        }
        __syncthreads();   // Q (first iter) + K visible

        // ---- S = Q K^T (2 rows x 4 keys per thread) ----
        float sacc[2][4] = {};
        #pragma unroll 8
        for (int k = 0; k < 128; ++k) {
            float2 a = *(const float2*)&Qs[k][ty << 1];
            float4 bf = *(const float4*)&Ks[k * 68 + (tx << 2)];
            sacc[0][0] = fmaf(a.x, bf.x, sacc[0][0]);
            sacc[0][1] = fmaf(a.x, bf.y, sacc[0][1]);
            sacc[0][2] = fmaf(a.x, bf.z, sacc[0][2]);
            sacc[0][3] = fmaf(a.x, bf.w, sacc[0][3]);
            sacc[1][0] = fmaf(a.y, bf.x, sacc[1][0]);
            sacc[1][1] = fmaf(a.y, bf.y, sacc[1][1]);
            sacc[1][2] = fmaf(a.y, bf.z, sacc[1][2]);
            sacc[1][3] = fmaf(a.y, bf.w, sacc[1][3]);
        }

        // ---- mask + online softmax ----
        #pragma unroll
        for (int i = 0; i < 2; ++i) {
            const int r = s0 + (ty << 1) + i;
            const int* erow = edge + (size_t)r * SS + t0 + (tx << 2);
            float sc[4];
            float tm = -INFINITY;
            #pragma unroll
            for (int j = 0; j < 4; ++j) {
                float v = sacc[i][j] * SCALE;
                v += (erow[j] == h + 1) ? 0.f : NEGF;
                sc[j] = v;
                tm = fmaxf(tm, v);
            }
            #pragma unroll
            for (int off = 1; off < 16; off <<= 1)
                tm = fmaxf(tm, __shfl_xor(tm, off, 16));
            float mn = fmaxf(m_[i], tm);
            float alpha = __expf(m_[i] - mn);
            float p0 = __expf(sc[0] - mn);
            float p1 = __expf(sc[1] - mn);
            float p2 = __expf(sc[2] - mn);
            float p3 = __expf(sc[3] - mn);
            float rs = p0 + p1 + p2 + p3;
            #pragma unroll
            for (int off = 1; off < 16; off <<= 1)
                rs += __shfl_xor(rs, off, 16);
            l_[i] = l_[i] * alpha + rs;
            m_[i] = mn;
            #pragma unroll
            for (int dd = 0; dd < 8; ++dd) o_[i][dd] *= alpha;
            float4 pw = make_float4(p0, p1, p2, p3);
            *(float4*)&Ps[(ty << 1) + i][tx << 2] = pw;
        }
        __syncthreads();   // K reads done, Ps visible

        // ---- load V tile (row-major, overwrites K region) ----
        float* Vs = KV;                 // [64][132]
        #pragma unroll
        for (int p = 0; p < 8; ++p) {
            int slot = tid + p * 256;
            int r  = slot >> 5;
            int c4 = (slot & 31) << 2;
            float4 v = *(const float4*)(qkb + (size_t)(t0 + r) * QKV_LD + 256 + c4);
            *(float4*)&Vs[r * 132 + c4] = v;
        }
        __syncthreads();   // V visible

        // ---- O += P V (2 rows x 8 dims per thread) ----
        #pragma unroll 4
        for (int t = 0; t < 64; ++t) {
            float p0 = Ps[(ty << 1) + 0][t];
            float p1 = Ps[(ty << 1) + 1][t];
            const float* vr = &Vs[t * 132 + (tx << 3)];
            float4 v0 = *(const float4*)vr;
            float4 v1 = *(const float4*)(vr + 4);
            float vv[8] = {v0.x, v0.y, v0.z, v0.w, v1.x, v1.y, v1.z, v1.w};
            #pragma unroll
            for (int dd = 0; dd < 8; ++dd) {
                o_[0][dd] = fmaf(p0, vv[dd], o_[0][dd]);
                o_[1][dd] = fmaf(p1, vv[dd], o_[1][dd]);
            }
        }
        __syncthreads();   // PV done before next K-tile overwrites Vs
    }

    // ---- epilogue: ctx = O / l ----
    #pragma unroll
    for (int i = 0; i < 2; ++i) {
        const int r = s0 + (ty << 1) + i;
        float inv = 1.0f / l_[i];
        float* cb = ctx + ((size_t)(b * NH + h) * SS + r) * Dh + (tx << 3);
        float4 u0 = make_float4(o_[i][0] * inv, o_[i][1] * inv, o_[i][2] * inv, o_[i][3] * inv);
        float4 u1 = make_float4(o_[i][4] * inv, o_[i][5] * inv, o_[i][6] * inv, o_[i][7] * inv);
        *(float4*)cb = u0;
        *(float4*)(cb + 4) = u1;
    }
}

// ---------------- K4: out projection (per head) ----------------
__global__ __launch_bounds__(256) void out_proj_kernel(const float* __restrict__ ctx,
                                                       const float* __restrict__ wo,  // [H][128][128]
                                                       const float* __restrict__ bo,  // [H][128]
                                                       float* __restrict__ out) {
    const int h = blockIdx.z;
    __shared__ float As[64][68];
    __shared__ float Bs[64][68];
    const int tid = threadIdx.x;
    const int tx = tid & 15, ty = tid >> 4;
    const int row0 = blockIdx.y * 64;    // global (b,s) row
    const int col0 = blockIdx.x * 64;    // e within head
    const int bb = row0 >> 10;
    const int sl = row0 & 1023;
    const float* abase = ctx + ((size_t)(bb * NH + h) * SS + sl) * Dh;
    const float* wbase = wo + (size_t)h * Dh * Dh + (size_t)col0 * Dh;
    float acc[4][4] = {};
    for (int kk = 0; kk < 128; kk += 64) {
        #pragma unroll
        for (int p = 0; p < 4; ++p) {
            int slot = tid + p * 256;
            int r  = slot >> 4;
            int c4 = (slot & 15) << 2;
            float4 v = *(const float4*)(abase + (size_t)r * Dh + kk + c4);
            As[c4 + 0][r] = v.x;
            As[c4 + 1][r] = v.y;
            As[c4 + 2][r] = v.z;
            As[c4 + 3][r] = v.w;
            float4 wv = *(const float4*)(wbase + (size_t)r * Dh + kk + c4);
            Bs[c4 + 0][r] = wv.x;
            Bs[c4 + 1][r] = wv.y;
            Bs[c4 + 2][r] = wv.z;
            Bs[c4 + 3][r] = wv.w;
        }
        __syncthreads();
        #pragma unroll 8
        for (int k = 0; k < 64; ++k) {
            float4 af = *(const float4*)&As[k][ty << 2];
            float4 bf = *(const float4*)&Bs[k][tx << 2];
            float a[4] = {af.x, af.y, af.z, af.w};
            float b[4] = {bf.x, bf.y, bf.z, bf.w};
            #pragma unroll
            for (int i = 0; i < 4; ++i)
                #pragma unroll
                for (int j = 0; j < 4; ++j)
                    acc[i][j] = fmaf(a[i], b[j], acc[i][j]);
        }
        __syncthreads();
    }
    const int n0 = col0 + (tx << 2);
    float4 bi = *(const float4*)(bo + h * Dh + n0);
    #pragma unroll
    for (int i = 0; i < 4; ++i) {
        int m = row0 + (ty << 2) + i;
        float4 o;
        o.x = acc[i][0] + bi.x;
        o.y = acc[i][1] + bi.y;
        o.z = acc[i][2] + bi.z;
        o.w = acc[i][3] + bi.w;
        *(float4*)(out + (size_t)m * (NH * Dh) + h * Dh + n0) = o;
    }
}

extern "C" void kernel_launch(void* const* d_in, const int* in_sizes, int n_in,
                              void* d_out, int out_size, void* d_ws, size_t ws_size,
                              hipStream_t stream) {
    const float* x     = (const float*)d_in[0];
    const int*   edge  = (const int*)d_in[1];    // int64 in ref; harness provides int32
    const float* w_in  = (const float*)d_in[2];  // [H][384][128] == [1536][128]
    const float* b_in  = (const float*)d_in[3];  // [1536]
    const float* w_out = (const float*)d_in[4];  // [H][128][128]
    const float* b_out = (const float*)d_in[5];  // [H][128]
    float* out = (float*)d_out;

    float* ws    = (float*)d_ws;
    float* stats = ws;                                   // 32 floats
    float* qkv   = ws + 64;                              // [16384][1536]
    float* ctx   = qkv + (size_t)NB * SS * QKV_LD;       // [B][H][S][128]

    ln_stats_kernel<<<NB, 256, 0, stream>>>(x, stats);
    qkv_proj_kernel<<<dim3(QKV_LD / 64, NB * SS / 64), 256, 0, stream>>>(x, w_in, b_in, stats, qkv);
    attn_kernel<<<dim3(SS / 32, NH, NB), 256, 0, stream>>>(qkv, edge, ctx);
    out_proj_kernel<<<dim3(Dh / 64, NB * SS / 64, NH), 256, 0, stream>>>(ctx, w_out, b_out, out);
}

// Round 2
// 461.132 us; speedup vs baseline: 2.2631x; 2.2631x over previous
//
#include <hip/hip_runtime.h>
#include <math.h>

static constexpr int Dh = 128;          // hidden/head dim
static constexpr int NH = 4;            // heads
static constexpr int NB = 16;           // batch
static constexpr int SS = 1024;         // seq len
static constexpr int QKV_LD = 3 * Dh * NH;   // 1536 cols of qkv matrix
static constexpr float NEGF = -1e9f;
static constexpr float SCALE = 0.08838834764831843f;  // 1/sqrt(128)

typedef short s16x8 __attribute__((ext_vector_type(8)));
typedef float f32x4 __attribute__((ext_vector_type(4)));

__device__ inline ushort f2bf(float f) {
    union { float f; unsigned u; } v; v.f = f;
    unsigned r = v.u + 0x7FFFu + ((v.u >> 16) & 1u);
    return (ushort)(r >> 16);
}

// ---------------- K1: layernorm stats (one block per batch) ----------------
__global__ __launch_bounds__(256) void ln_stats_kernel(const float* __restrict__ x,
                                                       float* __restrict__ stats) {
    const int b = blockIdx.x;
    const int tid = threadIdx.x;
    const int ND = SS * Dh;  // 131072
    const float4* xb = (const float4*)(x + (size_t)b * ND);
    float s = 0.f, ss = 0.f;
    for (int i = tid; i < ND / 4; i += 256) {
        float4 v = xb[i];
        s  += v.x + v.y + v.z + v.w;
        ss += v.x * v.x + v.y * v.y + v.z * v.z + v.w * v.w;
    }
    __shared__ float r1[256], r2[256];
    r1[tid] = s; r2[tid] = ss;
    __syncthreads();
    for (int off = 128; off > 0; off >>= 1) {
        if (tid < off) { r1[tid] += r1[tid + off]; r2[tid] += r2[tid + off]; }
        __syncthreads();
    }
    if (tid == 0) {
        float mu  = r1[0] / (float)ND;
        float var = r2[0] / (float)ND - mu * mu;
        stats[2 * b]     = mu;
        stats[2 * b + 1] = 1.0f / sqrtf(var + 1e-5f);
    }
}

// ---------------- K2: QKV projection GEMM (LN fused on A-load) ----------------
// writes q,k row-major bf16 [b][h][s][128]; v transposed bf16 [b][h][128][s]
__global__ __launch_bounds__(256) void qkv_proj_kernel(const float* __restrict__ x,
                                                       const float* __restrict__ w,   // [1536][128]
                                                       const float* __restrict__ bias,// [1536]
                                                       const float* __restrict__ stats,
                                                       ushort* __restrict__ qo,
                                                       ushort* __restrict__ ko,
                                                       ushort* __restrict__ vto) {
    __shared__ float As[64][68];  // k-major: As[k][row]
    __shared__ float Bs[64][68];  // k-major: Bs[k][col]
    const int tid = threadIdx.x;
    const int tx = tid & 15, ty = tid >> 4;
    const int row0 = blockIdx.y * 64;
    const int col0 = blockIdx.x * 64;
    const int bb = row0 >> 10;           // 64 | 1024 so tile is within one batch
    const float mu = stats[2 * bb], rstd = stats[2 * bb + 1];
    float acc[4][4] = {};
    for (int kk = 0; kk < 128; kk += 64) {
        #pragma unroll
        for (int p = 0; p < 4; ++p) {
            int slot = tid + p * 256;          // 0..1023 (64 rows x 16 float4)
            int r  = slot >> 4;
            int c4 = (slot & 15) << 2;
            float4 v = *(const float4*)(x + (size_t)(row0 + r) * Dh + kk + c4);
            As[c4 + 0][r] = (v.x - mu) * rstd;
            As[c4 + 1][r] = (v.y - mu) * rstd;
            As[c4 + 2][r] = (v.z - mu) * rstd;
            As[c4 + 3][r] = (v.w - mu) * rstd;
            float4 wv = *(const float4*)(w + (size_t)(col0 + r) * Dh + kk + c4);
            Bs[c4 + 0][r] = wv.x;
            Bs[c4 + 1][r] = wv.y;
            Bs[c4 + 2][r] = wv.z;
            Bs[c4 + 3][r] = wv.w;
        }
        __syncthreads();
        #pragma unroll 8
        for (int k = 0; k < 64; ++k) {
            float4 af = *(const float4*)&As[k][ty << 2];
            float4 bf = *(const float4*)&Bs[k][tx << 2];
            float a[4] = {af.x, af.y, af.z, af.w};
            float b[4] = {bf.x, bf.y, bf.z, bf.w};
            #pragma unroll
            for (int i = 0; i < 4; ++i)
                #pragma unroll
                for (int j = 0; j < 4; ++j)
                    acc[i][j] = fmaf(a[i], b[j], acc[i][j]);
        }
        __syncthreads();
    }
    const int n0 = col0 + (tx << 2);
    float4 bi = *(const float4*)(bias + n0);
    float bia[4] = {bi.x, bi.y, bi.z, bi.w};
    float ov[4][4];
    #pragma unroll
    for (int i = 0; i < 4; ++i)
        #pragma unroll
        for (int j = 0; j < 4; ++j)
            ov[i][j] = acc[i][j] + bia[j];

    const int hh  = col0 / 384;
    const int seg = col0 % 384;
    const int typ = seg >> 7;            // 0=q 1=k 2=v
    const int e0  = (seg & 127) + (tx << 2);
    const int sl  = (row0 & 1023) + (ty << 2);
    const size_t bh = (size_t)bb * NH + hh;
    if (typ < 2) {
        ushort* dst = (typ == 0 ? qo : ko) + bh * SS * 128;
        #pragma unroll
        for (int i = 0; i < 4; ++i) {
            ushort4 pk;
            pk.x = f2bf(ov[i][0]); pk.y = f2bf(ov[i][1]);
            pk.z = f2bf(ov[i][2]); pk.w = f2bf(ov[i][3]);
            *(ushort4*)&dst[(size_t)(sl + i) * 128 + e0] = pk;
        }
    } else {
        ushort* dst = vto + bh * 128 * SS;
        #pragma unroll
        for (int j = 0; j < 4; ++j) {
            ushort4 pk;
            pk.x = f2bf(ov[0][j]); pk.y = f2bf(ov[1][j]);
            pk.z = f2bf(ov[2][j]); pk.w = f2bf(ov[3][j]);
            *(ushort4*)&dst[(size_t)(e0 + j) * SS + sl] = pk;
        }
    }
}

// ---------------- K3: MFMA flash attention ----------------
// block = (64 q-rows, head, batch); 4 waves, each owns 16 rows.
static constexpr int KS_LD = 136;   // bf16 stride, pad 128+8 -> 2-way max conflicts
static constexpr int VT_LD = 72;    // 64+8
static constexpr int PS_LD = 72;

__global__ __launch_bounds__(256) void attn_mfma_kernel(const ushort* __restrict__ qg_,
                                                        const ushort* __restrict__ kg_,
                                                        const ushort* __restrict__ vg_,
                                                        const int* __restrict__ edge,
                                                        float* __restrict__ ctx) {
    const int qt = blockIdx.x, h = blockIdx.y, b = blockIdx.z;
    const int s0 = qt * 64;
    const int tid = threadIdx.x;
    const int wave = tid >> 6, lane = tid & 63;
    const int lrow = lane & 15, quad = lane >> 4;

    __shared__ ushort Ks[64 * KS_LD];    // [key][d]
    __shared__ ushort Vt[128 * VT_LD];   // [d][key]
    __shared__ ushort Ps[64 * PS_LD];    // [row][key], per-wave 16-row slabs

    const size_t bh = (size_t)(b * NH + h);
    const ushort* qg = qg_ + bh * SS * 128;
    const ushort* kg = kg_ + bh * SS * 128;
    const ushort* vg = vg_ + bh * 128 * SS;

    // Q fragments (A-operand): rows s0+16*wave+lrow, k = kc*32+quad*8
    s16x8 qf[4];
    {
        const ushort* qr = qg + (size_t)(s0 + 16 * wave + lrow) * 128 + quad * 8;
        #pragma unroll
        for (int kc = 0; kc < 4; ++kc) qf[kc] = *(const s16x8*)(qr + kc * 32);
    }

    f32x4 oacc[8];
    #pragma unroll
    for (int nb = 0; nb < 8; ++nb) oacc[nb] = (f32x4){0.f, 0.f, 0.f, 0.f};
    float m_run[4] = {-INFINITY, -INFINITY, -INFINITY, -INFINITY};
    float l_run[4] = {0.f, 0.f, 0.f, 0.f};

    for (int kt = 0; kt < 16; ++kt) {
        const int t0 = kt * 64;
        __syncthreads();   // previous iteration's Ks/Vt readers done
        // stage K tile: 64 x 128
        #pragma unroll
        for (int p = 0; p < 4; ++p) {
            int slot = tid + p * 256;           // 16 slots/row
            int r = slot >> 4, c = (slot & 15) * 8;
            s16x8 v = *(const s16x8*)(kg + (size_t)(t0 + r) * 128 + c);
            *(s16x8*)&Ks[r * KS_LD + c] = v;
        }
        // stage Vt tile: 128 x 64
        #pragma unroll
        for (int p = 0; p < 4; ++p) {
            int slot = tid + p * 256;           // 8 slots/row
            int r = slot >> 3, c = (slot & 7) * 8;
            s16x8 v = *(const s16x8*)(vg + (size_t)r * SS + t0 + c);
            *(s16x8*)&Vt[r * VT_LD + c] = v;
        }
        __syncthreads();

        // ---- S = Q K^T : 16 rows x 64 keys per wave ----
        f32x4 sacc[4];
        #pragma unroll
        for (int cb = 0; cb < 4; ++cb) {
            f32x4 a = (f32x4){0.f, 0.f, 0.f, 0.f};
            #pragma unroll
            for (int kc = 0; kc < 4; ++kc) {
                s16x8 bf = *(const s16x8*)&Ks[(16 * cb + lrow) * KS_LD + kc * 32 + quad * 8];
                a = __builtin_amdgcn_mfma_f32_16x16x32_bf16(qf[kc], bf, a, 0, 0, 0);
            }
            sacc[cb] = a;
        }

        // ---- mask + online softmax (rows quad*4+reg, 16 lanes per row-group) ----
        float alpha[4];
        #pragma unroll
        for (int reg = 0; reg < 4; ++reg) {
            const int rr = s0 + 16 * wave + quad * 4 + reg;
            float sv[4];
            float tm = -INFINITY;
            #pragma unroll
            for (int cb = 0; cb < 4; ++cb) {
                int tcol = t0 + 16 * cb + lrow;
                float v = sacc[cb][reg] * SCALE;
                v += (edge[(size_t)rr * SS + tcol] == h + 1) ? 0.f : NEGF;
                sv[cb] = v;
                tm = fmaxf(tm, v);
            }
            #pragma unroll
            for (int off = 1; off < 16; off <<= 1)
                tm = fmaxf(tm, __shfl_xor(tm, off, 16));
            float mn = fmaxf(m_run[reg], tm);
            float al = __expf(m_run[reg] - mn);
            float rs = 0.f;
            float pv[4];
            #pragma unroll
            for (int cb = 0; cb < 4; ++cb) {
                pv[cb] = __expf(sv[cb] - mn);
                rs += pv[cb];
            }
            #pragma unroll
            for (int off = 1; off < 16; off <<= 1)
                rs += __shfl_xor(rs, off, 16);
            l_run[reg] = l_run[reg] * al + rs;
            m_run[reg] = mn;
            alpha[reg] = al;
            #pragma unroll
            for (int cb = 0; cb < 4; ++cb)
                Ps[(16 * wave + quad * 4 + reg) * PS_LD + 16 * cb + lrow] = f2bf(pv[cb]);
        }
        // rescale O
        #pragma unroll
        for (int nb = 0; nb < 8; ++nb)
            #pragma unroll
            for (int reg = 0; reg < 4; ++reg)
                oacc[nb][reg] *= alpha[reg];

        // ---- O += P V  (per-wave Ps slab; same-wave LDS RAW is in-order) ----
        s16x8 af[2];
        af[0] = *(const s16x8*)&Ps[(16 * wave + lrow) * PS_LD + quad * 8];
        af[1] = *(const s16x8*)&Ps[(16 * wave + lrow) * PS_LD + 32 + quad * 8];
        #pragma unroll
        for (int nb = 0; nb < 8; ++nb) {
            #pragma unroll
            for (int kc = 0; kc < 2; ++kc) {
                s16x8 bf = *(const s16x8*)&Vt[(16 * nb + lrow) * VT_LD + kc * 32 + quad * 8];
                oacc[nb] = __builtin_amdgcn_mfma_f32_16x16x32_bf16(af[kc], bf, oacc[nb], 0, 0, 0);
            }
        }
    }

    // ---- epilogue: ctx = O / l (fp32) ----
    float inv[4];
    #pragma unroll
    for (int reg = 0; reg < 4; ++reg) inv[reg] = 1.0f / l_run[reg];
    float* cb_ = ctx + (bh * SS + s0 + 16 * wave) * Dh;
    #pragma unroll
    for (int nb = 0; nb < 8; ++nb)
        #pragma unroll
        for (int reg = 0; reg < 4; ++reg)
            cb_[(size_t)(quad * 4 + reg) * Dh + 16 * nb + lrow] = oacc[nb][reg] * inv[reg];
}

// ---------------- K4: out projection (per head) ----------------
__global__ __launch_bounds__(256) void out_proj_kernel(const float* __restrict__ ctx,
                                                       const float* __restrict__ wo,  // [H][128][128]
                                                       const float* __restrict__ bo,  // [H][128]
                                                       float* __restrict__ out) {
    const int h = blockIdx.z;
    __shared__ float As[64][68];
    __shared__ float Bs[64][68];
    const int tid = threadIdx.x;
    const int tx = tid & 15, ty = tid >> 4;
    const int row0 = blockIdx.y * 64;    // global (b,s) row
    const int col0 = blockIdx.x * 64;    // e within head
    const int bb = row0 >> 10;
    const int sl = row0 & 1023;
    const float* abase = ctx + ((size_t)(bb * NH + h) * SS + sl) * Dh;
    const float* wbase = wo + (size_t)h * Dh * Dh + (size_t)col0 * Dh;
    float acc[4][4] = {};
    for (int kk = 0; kk < 128; kk += 64) {
        #pragma unroll
        for (int p = 0; p < 4; ++p) {
            int slot = tid + p * 256;
            int r  = slot >> 4;
            int c4 = (slot & 15) << 2;
            float4 v = *(const float4*)(abase + (size_t)r * Dh + kk + c4);
            As[c4 + 0][r] = v.x;
            As[c4 + 1][r] = v.y;
            As[c4 + 2][r] = v.z;
            As[c4 + 3][r] = v.w;
            float4 wv = *(const float4*)(wbase + (size_t)r * Dh + kk + c4);
            Bs[c4 + 0][r] = wv.x;
            Bs[c4 + 1][r] = wv.y;
            Bs[c4 + 2][r] = wv.z;
            Bs[c4 + 3][r] = wv.w;
        }
        __syncthreads();
        #pragma unroll 8
        for (int k = 0; k < 64; ++k) {
            float4 af = *(const float4*)&As[k][ty << 2];
            float4 bf = *(const float4*)&Bs[k][tx << 2];
            float a[4] = {af.x, af.y, af.z, af.w};
            float b[4] = {bf.x, bf.y, bf.z, bf.w};
            #pragma unroll
            for (int i = 0; i < 4; ++i)
                #pragma unroll
                for (int j = 0; j < 4; ++j)
                    acc[i][j] = fmaf(a[i], b[j], acc[i][j]);
        }
        __syncthreads();
    }
    const int n0 = col0 + (tx << 2);
    float4 bi = *(const float4*)(bo + h * Dh + n0);
    #pragma unroll
    for (int i = 0; i < 4; ++i) {
        int m = row0 + (ty << 2) + i;
        float4 o;
        o.x = acc[i][0] + bi.x;
        o.y = acc[i][1] + bi.y;
        o.z = acc[i][2] + bi.z;
        o.w = acc[i][3] + bi.w;
        *(float4*)(out + (size_t)m * (NH * Dh) + h * Dh + n0) = o;
    }
}

extern "C" void kernel_launch(void* const* d_in, const int* in_sizes, int n_in,
                              void* d_out, int out_size, void* d_ws, size_t ws_size,
                              hipStream_t stream) {
    const float* x     = (const float*)d_in[0];
    const int*   edge  = (const int*)d_in[1];    // int64 in ref; harness provides int32
    const float* w_in  = (const float*)d_in[2];  // [1536][128]
    const float* b_in  = (const float*)d_in[3];  // [1536]
    const float* w_out = (const float*)d_in[4];  // [H][128][128]
    const float* b_out = (const float*)d_in[5];  // [H][128]
    float* out = (float*)d_out;

    float* ws    = (float*)d_ws;
    float* stats = ws;                                   // 32 floats (pad to 64)
    ushort* qo   = (ushort*)(ws + 64);                   // [B][H][S][128] bf16
    const size_t QSZ = (size_t)NB * NH * SS * 128;
    ushort* ko   = qo + QSZ;
    ushort* vto  = ko + QSZ;                             // [B][H][128][S] bf16
    float* ctx   = (float*)(vto + QSZ);                  // [B][H][S][128] fp32

    ln_stats_kernel<<<NB, 256, 0, stream>>>(x, stats);
    qkv_proj_kernel<<<dim3(QKV_LD / 64, NB * SS / 64), 256, 0, stream>>>(x, w_in, b_in, stats, qo, ko, vto);
    attn_mfma_kernel<<<dim3(SS / 64, NH, NB), 256, 0, stream>>>(qo, ko, vto, edge, ctx);
    out_proj_kernel<<<dim3(Dh / 64, NB * SS / 64, NH), 256, 0, stream>>>(ctx, w_out, b_out, out);
}

// Round 3
// 292.816 us; speedup vs baseline: 3.5640x; 1.5748x over previous
//
#include <hip/hip_runtime.h>
#include <math.h>

static constexpr int Dh = 128;
static constexpr int NH = 4;
static constexpr int NB = 16;
static constexpr int SS = 1024;
static constexpr float NEGF = -1e9f;
static constexpr float SCALE = 0.08838834764831843f;  // 1/sqrt(128)

typedef short s16x8 __attribute__((ext_vector_type(8)));
typedef float f32x4 __attribute__((ext_vector_type(4)));

__device__ inline ushort f2bf(float f) {
    union { float f; unsigned u; } v; v.f = f;
    unsigned r = v.u + 0x7FFFu + ((v.u >> 16) & 1u);
    return (ushort)(r >> 16);
}
__device__ inline float bf2f(ushort h) {
    union { unsigned u; float f; } v; v.u = (unsigned)h << 16;
    return v.f;
}

// ---------------- K0a: LN partial sums (16 parts per batch) ----------------
__global__ __launch_bounds__(256) void ln_part_kernel(const float* __restrict__ x,
                                                      float* __restrict__ part) {
    const int b = blockIdx.x >> 4, p = blockIdx.x & 15;
    const int tid = threadIdx.x;
    const float4* xb = (const float4*)(x + (size_t)b * SS * Dh) + p * 2048;
    float s = 0.f, ss = 0.f;
    for (int i = tid; i < 2048; i += 256) {
        float4 v = xb[i];
        s  += v.x + v.y + v.z + v.w;
        ss += v.x * v.x + v.y * v.y + v.z * v.z + v.w * v.w;
    }
    __shared__ float r1[256], r2[256];
    r1[tid] = s; r2[tid] = ss;
    __syncthreads();
    for (int off = 128; off > 0; off >>= 1) {
        if (tid < off) { r1[tid] += r1[tid + off]; r2[tid] += r2[tid + off]; }
        __syncthreads();
    }
    if (tid == 0) { part[blockIdx.x * 2] = r1[0]; part[blockIdx.x * 2 + 1] = r2[0]; }
}

// ---------------- K0b: LN finalize ----------------
__global__ void ln_final_kernel(const float* __restrict__ part, float* __restrict__ stats) {
    int b = threadIdx.x;
    if (b < NB) {
        float s = 0.f, ss = 0.f;
        for (int p = 0; p < 16; ++p) { s += part[(b * 16 + p) * 2]; ss += part[(b * 16 + p) * 2 + 1]; }
        const float inv = 1.0f / (float)(SS * Dh);
        float mu = s * inv;
        float var = ss * inv - mu * mu;
        stats[2 * b] = mu;
        stats[2 * b + 1] = 1.0f / sqrtf(var + 1e-5f);
    }
}

// ---------------- K0c: mask bias prep: mb[h][s][t] bf16 in {0, -1e9} ----------------
__global__ __launch_bounds__(256) void mask_prep_kernel(const int* __restrict__ edge,
                                                        ushort* __restrict__ mb) {
    const int i = blockIdx.x * 256 + threadIdx.x;   // < SS*SS/4
    int4 e = ((const int4*)edge)[i];
    const ushort NEGB = f2bf(NEGF);
    #pragma unroll
    for (int h = 0; h < 4; ++h) {
        ushort4 m;
        m.x = (e.x == h + 1) ? (ushort)0 : NEGB;
        m.y = (e.y == h + 1) ? (ushort)0 : NEGB;
        m.z = (e.z == h + 1) ? (ushort)0 : NEGB;
        m.w = (e.w == h + 1) ? (ushort)0 : NEGB;
        ((ushort4*)(mb + (size_t)h * SS * SS))[i] = m;
    }
}

// ---------------- K1: QKV projection, bf16 MFMA (LN fused on A-stage) ----------------
// q pre-scaled by 1/sqrt(D). q,k row-major bf16 [b][h][s][128]; v transposed [b][h][128][s].
__global__ __launch_bounds__(256) void qkv_mfma_kernel(const float* __restrict__ x,
                                                       const float* __restrict__ w,    // [1536][128]
                                                       const float* __restrict__ bias, // [1536]
                                                       const float* __restrict__ stats,
                                                       ushort* __restrict__ qo,
                                                       ushort* __restrict__ ko,
                                                       ushort* __restrict__ vto) {
    __shared__ ushort As[128 * 72];   // [m][k-half] stride 72 -> 2-way-free b128 reads
    __shared__ ushort Bs[128 * 72];   // [n][k-half]
    const int tid = threadIdx.x, wave = tid >> 6, lane = tid & 63;
    const int lrow = lane & 15, quad = lane >> 4;
    const int wm = wave & 1, wn = wave >> 1;
    const int col0 = blockIdx.x * 128;   // n-tile (within [1536])
    const int row0 = blockIdx.y * 128;   // m-tile (within [16384]); 128|1024 -> one batch
    const int bb = row0 >> 10;
    const float mu = stats[2 * bb], rstd = stats[2 * bb + 1];

    f32x4 acc[4][4];
    #pragma unroll
    for (int mi = 0; mi < 4; ++mi)
        #pragma unroll
        for (int ni = 0; ni < 4; ++ni) acc[mi][ni] = (f32x4){0.f, 0.f, 0.f, 0.f};

    for (int kk = 0; kk < 128; kk += 64) {
        if (kk) __syncthreads();
        #pragma unroll
        for (int p = 0; p < 8; ++p) {
            int slot = p * 256 + tid;          // 2048 slots: 128 rows x 16 float4
            int r = slot >> 4, c4 = (slot & 15) << 2;
            float4 v = *(const float4*)(x + (size_t)(row0 + r) * Dh + kk + c4);
            ushort4 pa;
            pa.x = f2bf((v.x - mu) * rstd); pa.y = f2bf((v.y - mu) * rstd);
            pa.z = f2bf((v.z - mu) * rstd); pa.w = f2bf((v.w - mu) * rstd);
            *(ushort4*)&As[r * 72 + c4] = pa;
            float4 wv = *(const float4*)(w + (size_t)(col0 + r) * Dh + kk + c4);
            ushort4 pb;
            pb.x = f2bf(wv.x); pb.y = f2bf(wv.y); pb.z = f2bf(wv.z); pb.w = f2bf(wv.w);
            *(ushort4*)&Bs[r * 72 + c4] = pb;
        }
        __syncthreads();
        #pragma unroll
        for (int kc = 0; kc < 2; ++kc) {
            s16x8 af[4], bf[4];
            #pragma unroll
            for (int mi = 0; mi < 4; ++mi)
                af[mi] = *(const s16x8*)&As[(wm * 64 + 16 * mi + lrow) * 72 + kc * 32 + quad * 8];
            #pragma unroll
            for (int ni = 0; ni < 4; ++ni)
                bf[ni] = *(const s16x8*)&Bs[(wn * 64 + 16 * ni + lrow) * 72 + kc * 32 + quad * 8];
            #pragma unroll
            for (int mi = 0; mi < 4; ++mi)
                #pragma unroll
                for (int ni = 0; ni < 4; ++ni)
                    acc[mi][ni] = __builtin_amdgcn_mfma_f32_16x16x32_bf16(af[mi], bf[ni], acc[mi][ni], 0, 0, 0);
        }
    }

    const int seg = col0 % 384, typ = seg >> 7, h = col0 / 384;
    const size_t bh = (size_t)bb * NH + h;
    const int sl0 = (row0 & 1023) + wm * 64;   // s within batch for this wave
    const int cb0 = (seg & 127) + wn * 64;     // e within head for this wave
    float bia[4];
    #pragma unroll
    for (int ni = 0; ni < 4; ++ni) bia[ni] = bias[col0 + wn * 64 + 16 * ni + lrow];

    if (typ < 2) {
        ushort* dst = (typ == 0 ? qo : ko) + bh * SS * 128;
        const float sc = (typ == 0) ? SCALE : 1.f;
        #pragma unroll
        for (int mi = 0; mi < 4; ++mi)
            #pragma unroll
            for (int ni = 0; ni < 4; ++ni)
                #pragma unroll
                for (int reg = 0; reg < 4; ++reg) {
                    int s = sl0 + 16 * mi + quad * 4 + reg;
                    int e = cb0 + 16 * ni + lrow;
                    dst[(size_t)s * 128 + e] = f2bf((acc[mi][ni][reg] + bia[ni]) * sc);
                }
    } else {
        ushort* dst = vto + bh * (size_t)128 * SS;
        #pragma unroll
        for (int mi = 0; mi < 4; ++mi)
            #pragma unroll
            for (int ni = 0; ni < 4; ++ni) {
                int e = cb0 + 16 * ni + lrow;
                int s = sl0 + 16 * mi + quad * 4;
                ushort4 pk;
                pk.x = f2bf(acc[mi][ni][0] + bia[ni]);
                pk.y = f2bf(acc[mi][ni][1] + bia[ni]);
                pk.z = f2bf(acc[mi][ni][2] + bia[ni]);
                pk.w = f2bf(acc[mi][ni][3] + bia[ni]);
                *(ushort4*)&dst[(size_t)e * SS + s] = pk;
            }
    }
}

// ---------------- K2: MFMA flash attention ----------------
static constexpr int KS_LD = 136;   // stride%64==8 -> 2-way-free b128 frag reads
static constexpr int VT_LD = 72;
static constexpr int PS_LD = 72;

__global__ __launch_bounds__(256) void attn_mfma_kernel(const ushort* __restrict__ qg_,
                                                        const ushort* __restrict__ kg_,
                                                        const ushort* __restrict__ vg_,
                                                        const ushort* __restrict__ mb,
                                                        ushort* __restrict__ ctx) {
    const int qt = blockIdx.x, h = blockIdx.y, b = blockIdx.z;
    const int s0 = qt * 64;
    const int tid = threadIdx.x;
    const int wave = tid >> 6, lane = tid & 63;
    const int lrow = lane & 15, quad = lane >> 4;

    __shared__ ushort Ks[64 * KS_LD];    // [key][d]
    __shared__ ushort Vt[128 * VT_LD];   // [d][key]
    __shared__ ushort Ps[64 * PS_LD];    // mask tile -> probabilities, in place

    const size_t bh = (size_t)(b * NH + h);
    const ushort* qg = qg_ + bh * SS * 128;
    const ushort* kg = kg_ + bh * SS * 128;
    const ushort* vg = vg_ + bh * 128 * SS;
    const ushort* mh = mb + (size_t)h * SS * SS;

    // Q fragments (A-operand): rows s0+16*wave+lrow (q pre-scaled by 1/sqrt(D))
    s16x8 qf[4];
    {
        const ushort* qr = qg + (size_t)(s0 + 16 * wave + lrow) * 128 + quad * 8;
        #pragma unroll
        for (int kc = 0; kc < 4; ++kc) qf[kc] = *(const s16x8*)(qr + kc * 32);
    }

    f32x4 oacc[8];
    #pragma unroll
    for (int nb = 0; nb < 8; ++nb) oacc[nb] = (f32x4){0.f, 0.f, 0.f, 0.f};
    float m_run[4] = {-INFINITY, -INFINITY, -INFINITY, -INFINITY};
    float l_run[4] = {0.f, 0.f, 0.f, 0.f};

    for (int kt = 0; kt < 16; ++kt) {
        const int t0 = kt * 64;
        __syncthreads();   // previous iteration's readers done
        // stage K tile 64x128
        #pragma unroll
        for (int p = 0; p < 4; ++p) {
            int slot = p * 256 + tid;
            int r = slot >> 4, c = (slot & 15) * 8;
            s16x8 v = *(const s16x8*)(kg + (size_t)(t0 + r) * 128 + c);
            *(s16x8*)&Ks[r * KS_LD + c] = v;
        }
        // stage Vt tile 128x64
        #pragma unroll
        for (int p = 0; p < 4; ++p) {
            int slot = p * 256 + tid;
            int r = slot >> 3, c = (slot & 7) * 8;
            s16x8 v = *(const s16x8*)(vg + (size_t)r * SS + t0 + c);
            *(s16x8*)&Vt[r * VT_LD + c] = v;
        }
        // stage mask tile 64x64 into Ps region
        #pragma unroll
        for (int p = 0; p < 2; ++p) {
            int slot = p * 256 + tid;
            int r = slot >> 3, c = (slot & 7) * 8;
            s16x8 v = *(const s16x8*)(mh + (size_t)(s0 + r) * SS + t0 + c);
            *(s16x8*)&Ps[r * PS_LD + c] = v;
        }
        __syncthreads();

        // ---- S = (q/sqrtD) K^T + mask : init acc from mask tile ----
        f32x4 sacc[4];
        #pragma unroll
        for (int cb = 0; cb < 4; ++cb) {
            #pragma unroll
            for (int reg = 0; reg < 4; ++reg)
                sacc[cb][reg] = bf2f(Ps[(16 * wave + quad * 4 + reg) * PS_LD + 16 * cb + lrow]);
        }
        #pragma unroll
        for (int cb = 0; cb < 4; ++cb) {
            #pragma unroll
            for (int kc = 0; kc < 4; ++kc) {
                s16x8 bf = *(const s16x8*)&Ks[(16 * cb + lrow) * KS_LD + kc * 32 + quad * 8];
                sacc[cb] = __builtin_amdgcn_mfma_f32_16x16x32_bf16(qf[kc], bf, sacc[cb], 0, 0, 0);
            }
        }

        // ---- online softmax (no global traffic, no mask/scale ops) ----
        float alpha[4];
        #pragma unroll
        for (int reg = 0; reg < 4; ++reg) {
            float tm = fmaxf(fmaxf(sacc[0][reg], sacc[1][reg]),
                             fmaxf(sacc[2][reg], sacc[3][reg]));
            #pragma unroll
            for (int off = 1; off < 16; off <<= 1)
                tm = fmaxf(tm, __shfl_xor(tm, off, 16));
            float mn = fmaxf(m_run[reg], tm);
            float al = __expf(m_run[reg] - mn);
            float pv[4], rs = 0.f;
            #pragma unroll
            for (int cb = 0; cb < 4; ++cb) {
                pv[cb] = __expf(sacc[cb][reg] - mn);
                rs += pv[cb];
            }
            #pragma unroll
            for (int off = 1; off < 16; off <<= 1)
                rs += __shfl_xor(rs, off, 16);
            l_run[reg] = l_run[reg] * al + rs;
            m_run[reg] = mn;
            alpha[reg] = al;
            #pragma unroll
            for (int cb = 0; cb < 4; ++cb)
                Ps[(16 * wave + quad * 4 + reg) * PS_LD + 16 * cb + lrow] = f2bf(pv[cb]);
        }
        #pragma unroll
        for (int nb = 0; nb < 8; ++nb)
            #pragma unroll
            for (int reg = 0; reg < 4; ++reg)
                oacc[nb][reg] *= alpha[reg];

        // ---- O += P V (per-wave Ps slab; same-wave LDS RAW in-order) ----
        s16x8 af0 = *(const s16x8*)&Ps[(16 * wave + lrow) * PS_LD + quad * 8];
        s16x8 af1 = *(const s16x8*)&Ps[(16 * wave + lrow) * PS_LD + 32 + quad * 8];
        #pragma unroll
        for (int nb = 0; nb < 8; ++nb) {
            s16x8 bf0 = *(const s16x8*)&Vt[(16 * nb + lrow) * VT_LD + quad * 8];
            oacc[nb] = __builtin_amdgcn_mfma_f32_16x16x32_bf16(af0, bf0, oacc[nb], 0, 0, 0);
            s16x8 bf1 = *(const s16x8*)&Vt[(16 * nb + lrow) * VT_LD + 32 + quad * 8];
            oacc[nb] = __builtin_amdgcn_mfma_f32_16x16x32_bf16(af1, bf1, oacc[nb], 0, 0, 0);
        }
    }

    // ---- epilogue: ctx = O / l, bf16 ----
    float inv[4];
    #pragma unroll
    for (int reg = 0; reg < 4; ++reg) inv[reg] = 1.0f / l_run[reg];
    ushort* cb_ = ctx + (bh * SS + s0 + 16 * wave) * Dh;
    #pragma unroll
    for (int nb = 0; nb < 8; ++nb)
        #pragma unroll
        for (int reg = 0; reg < 4; ++reg)
            cb_[(size_t)(quad * 4 + reg) * Dh + 16 * nb + lrow] = f2bf(oacc[nb][reg] * inv[reg]);
}

// ---------------- K3: out projection, bf16 MFMA ----------------
__global__ __launch_bounds__(256) void out_mfma_kernel(const ushort* __restrict__ ctx,
                                                       const float* __restrict__ wo,  // [H][128][128]
                                                       const float* __restrict__ bo,  // [H][128]
                                                       float* __restrict__ out) {
    __shared__ ushort As[128 * 72];
    __shared__ ushort Bs[128 * 72];
    const int tid = threadIdx.x, wave = tid >> 6, lane = tid & 63;
    const int lrow = lane & 15, quad = lane >> 4;
    const int wm = wave & 1, wn = wave >> 1;
    const int h = blockIdx.x;
    const int row0 = blockIdx.y * 128;
    const int bb = row0 >> 10, sl = row0 & 1023;
    const ushort* abase = ctx + ((size_t)(bb * NH + h) * SS + sl) * Dh;
    const float* wbase = wo + (size_t)h * Dh * Dh;

    f32x4 acc[4][4];
    #pragma unroll
    for (int mi = 0; mi < 4; ++mi)
        #pragma unroll
        for (int ni = 0; ni < 4; ++ni) acc[mi][ni] = (f32x4){0.f, 0.f, 0.f, 0.f};

    for (int kk = 0; kk < 128; kk += 64) {
        if (kk) __syncthreads();
        #pragma unroll
        for (int p = 0; p < 4; ++p) {          // A: 128 rows x 8 granules bf16
            int slot = p * 256 + tid;
            int r = slot >> 3, c8 = (slot & 7) * 8;
            *(s16x8*)&As[r * 72 + c8] = *(const s16x8*)(abase + (size_t)r * Dh + kk + c8);
        }
        #pragma unroll
        for (int p = 0; p < 8; ++p) {          // B: 128 rows x 16 float4 fp32 -> bf16
            int slot = p * 256 + tid;
            int r = slot >> 4, c4 = (slot & 15) << 2;
            float4 wv = *(const float4*)(wbase + (size_t)r * Dh + kk + c4);
            ushort4 pb;
            pb.x = f2bf(wv.x); pb.y = f2bf(wv.y); pb.z = f2bf(wv.z); pb.w = f2bf(wv.w);
            *(ushort4*)&Bs[r * 72 + c4] = pb;
        }
        __syncthreads();
        #pragma unroll
        for (int kc = 0; kc < 2; ++kc) {
            s16x8 af[4], bf[4];
            #pragma unroll
            for (int mi = 0; mi < 4; ++mi)
                af[mi] = *(const s16x8*)&As[(wm * 64 + 16 * mi + lrow) * 72 + kc * 32 + quad * 8];
            #pragma unroll
            for (int ni = 0; ni < 4; ++ni)
                bf[ni] = *(const s16x8*)&Bs[(wn * 64 + 16 * ni + lrow) * 72 + kc * 32 + quad * 8];
            #pragma unroll
            for (int mi = 0; mi < 4; ++mi)
                #pragma unroll
                for (int ni = 0; ni < 4; ++ni)
                    acc[mi][ni] = __builtin_amdgcn_mfma_f32_16x16x32_bf16(af[mi], bf[ni], acc[mi][ni], 0, 0, 0);
        }
    }

    float bia[4];
    #pragma unroll
    for (int ni = 0; ni < 4; ++ni) bia[ni] = bo[h * Dh + wn * 64 + 16 * ni + lrow];
    #pragma unroll
    for (int mi = 0; mi < 4; ++mi)
        #pragma unroll
        for (int ni = 0; ni < 4; ++ni)
            #pragma unroll
            for (int reg = 0; reg < 4; ++reg) {
                int m = row0 + wm * 64 + 16 * mi + quad * 4 + reg;
                int e = wn * 64 + 16 * ni + lrow;
                out[(size_t)m * (NH * Dh) + h * Dh + e] = acc[mi][ni][reg] + bia[ni];
            }
}

extern "C" void kernel_launch(void* const* d_in, const int* in_sizes, int n_in,
                              void* d_out, int out_size, void* d_ws, size_t ws_size,
                              hipStream_t stream) {
    const float* x     = (const float*)d_in[0];
    const int*   edge  = (const int*)d_in[1];
    const float* w_in  = (const float*)d_in[2];
    const float* b_in  = (const float*)d_in[3];
    const float* w_out = (const float*)d_in[4];
    const float* b_out = (const float*)d_in[5];
    float* out = (float*)d_out;

    float* ws    = (float*)d_ws;
    float* stats = ws;                       // 32
    float* part  = ws + 32;                  // 512
    ushort* mb   = (ushort*)(ws + 1024);     // [4][1024][1024] bf16
    const size_t QSZ = (size_t)NB * NH * SS * 128;
    ushort* qo  = mb + (size_t)NH * SS * SS;
    ushort* ko  = qo + QSZ;
    ushort* vto = ko + QSZ;                  // [b][h][128][s]
    ushort* ctx = vto + QSZ;                 // [b][h][s][128] bf16

    ln_part_kernel<<<256, 256, 0, stream>>>(x, part);
    ln_final_kernel<<<1, 64, 0, stream>>>(part, stats);
    mask_prep_kernel<<<SS * SS / 4 / 256, 256, 0, stream>>>(edge, mb);
    qkv_mfma_kernel<<<dim3(12, 128), 256, 0, stream>>>(x, w_in, b_in, stats, qo, ko, vto);
    attn_mfma_kernel<<<dim3(SS / 64, NH, NB), 256, 0, stream>>>(qo, ko, vto, mb, ctx);
    out_mfma_kernel<<<dim3(NH, 128), 256, 0, stream>>>(ctx, w_out, b_out, out);
}

// Round 7
// 214.449 us; speedup vs baseline: 4.8664x; 1.3654x over previous
//
#include <hip/hip_runtime.h>
#include <math.h>

static constexpr int Dh = 128;
static constexpr int NH = 4;
static constexpr int NB = 16;
static constexpr int SS = 1024;
static constexpr float NEGF = -1e9f;
static constexpr float SCALE = 0.08838834764831843f;  // 1/sqrt(128)

typedef short s16x8 __attribute__((ext_vector_type(8)));
typedef float f32x4 __attribute__((ext_vector_type(4)));

#define MFMA32(a, b, c) __builtin_amdgcn_mfma_f32_16x16x32_bf16(a, b, c, 0, 0, 0)

__device__ inline ushort f2bf(float f) {
    union { float f; unsigned u; } v; v.f = f;
    unsigned r = v.u + 0x7FFFu + ((v.u >> 16) & 1u);
    return (ushort)(r >> 16);
}
__device__ inline float bf2f(ushort h) {
    union { unsigned u; float f; } v; v.u = (unsigned)h << 16;
    return v.f;
}

// ---------------- K0a: LN partial sums (16 parts per batch) ----------------
__global__ __launch_bounds__(256) void ln_part_kernel(const float* __restrict__ x,
                                                      float* __restrict__ part) {
    const int b = blockIdx.x >> 4, p = blockIdx.x & 15;
    const int tid = threadIdx.x;
    const float4* xb = (const float4*)(x + (size_t)b * SS * Dh) + p * 2048;
    float s = 0.f, ss = 0.f;
    for (int i = tid; i < 2048; i += 256) {
        float4 v = xb[i];
        s  += v.x + v.y + v.z + v.w;
        ss += v.x * v.x + v.y * v.y + v.z * v.z + v.w * v.w;
    }
    __shared__ float r1[256], r2[256];
    r1[tid] = s; r2[tid] = ss;
    __syncthreads();
    for (int off = 128; off > 0; off >>= 1) {
        if (tid < off) { r1[tid] += r1[tid + off]; r2[tid] += r2[tid + off]; }
        __syncthreads();
    }
    if (tid == 0) { part[blockIdx.x * 2] = r1[0]; part[blockIdx.x * 2 + 1] = r2[0]; }
}

// ---------------- K0b: LN finalize ----------------
__global__ void ln_final_kernel(const float* __restrict__ part, float* __restrict__ stats) {
    int b = threadIdx.x;
    if (b < NB) {
        float s = 0.f, ss = 0.f;
        for (int p = 0; p < 16; ++p) { s += part[(b * 16 + p) * 2]; ss += part[(b * 16 + p) * 2 + 1]; }
        const float inv = 1.0f / (float)(SS * Dh);
        float mu = s * inv;
        float var = ss * inv - mu * mu;
        stats[2 * b] = mu;
        stats[2 * b + 1] = 1.0f / sqrtf(var + 1e-5f);
    }
}

// ---------------- K0c: mask bias prep: mb[h][s][t] bf16 in {0, -1e9} ----------------
__global__ __launch_bounds__(256) void mask_prep_kernel(const int* __restrict__ edge,
                                                        ushort* __restrict__ mb) {
    const int i = blockIdx.x * 256 + threadIdx.x;   // < SS*SS/4
    int4 e = ((const int4*)edge)[i];
    const ushort NEGB = f2bf(NEGF);
    #pragma unroll
    for (int h = 0; h < 4; ++h) {
        ushort4 m;
        m.x = (e.x == h + 1) ? (ushort)0 : NEGB;
        m.y = (e.y == h + 1) ? (ushort)0 : NEGB;
        m.z = (e.z == h + 1) ? (ushort)0 : NEGB;
        m.w = (e.w == h + 1) ? (ushort)0 : NEGB;
        ((ushort4*)(mb + (size_t)h * SS * SS))[i] = m;
    }
}

// ---------------- K1: QKV projection, bf16 MFMA (LN fused on A-stage) ----------------
// q pre-scaled by 1/sqrt(D). q,k row-major bf16 [b][h][s][128]; v transposed [b][h][128][s].
__global__ __launch_bounds__(256) void qkv_mfma_kernel(const float* __restrict__ x,
                                                       const float* __restrict__ w,    // [1536][128]
                                                       const float* __restrict__ bias, // [1536]
                                                       const float* __restrict__ stats,
                                                       ushort* __restrict__ qo,
                                                       ushort* __restrict__ ko,
                                                       ushort* __restrict__ vto) {
    __shared__ ushort As[128 * 72];
    __shared__ ushort Bs[128 * 72];
    const int tid = threadIdx.x, wave = tid >> 6, lane = tid & 63;
    const int lrow = lane & 15, quad = lane >> 4;
    const int wm = wave & 1, wn = wave >> 1;
    const int col0 = blockIdx.x * 128;
    const int row0 = blockIdx.y * 128;
    const int bb = row0 >> 10;
    const float mu = stats[2 * bb], rstd = stats[2 * bb + 1];

    f32x4 acc[4][4];
    #pragma unroll
    for (int mi = 0; mi < 4; ++mi)
        #pragma unroll
        for (int ni = 0; ni < 4; ++ni) acc[mi][ni] = (f32x4){0.f, 0.f, 0.f, 0.f};

    for (int kk = 0; kk < 128; kk += 64) {
        if (kk) __syncthreads();
        #pragma unroll
        for (int p = 0; p < 8; ++p) {
            int slot = p * 256 + tid;
            int r = slot >> 4, c4 = (slot & 15) << 2;
            float4 v = *(const float4*)(x + (size_t)(row0 + r) * Dh + kk + c4);
            ushort4 pa;
            pa.x = f2bf((v.x - mu) * rstd); pa.y = f2bf((v.y - mu) * rstd);
            pa.z = f2bf((v.z - mu) * rstd); pa.w = f2bf((v.w - mu) * rstd);
            *(ushort4*)&As[r * 72 + c4] = pa;
            float4 wv = *(const float4*)(w + (size_t)(col0 + r) * Dh + kk + c4);
            ushort4 pb;
            pb.x = f2bf(wv.x); pb.y = f2bf(wv.y); pb.z = f2bf(wv.z); pb.w = f2bf(wv.w);
            *(ushort4*)&Bs[r * 72 + c4] = pb;
        }
        __syncthreads();
        #pragma unroll
        for (int kc = 0; kc < 2; ++kc) {
            s16x8 af[4], bf[4];
            #pragma unroll
            for (int mi = 0; mi < 4; ++mi)
                af[mi] = *(const s16x8*)&As[(wm * 64 + 16 * mi + lrow) * 72 + kc * 32 + quad * 8];
            #pragma unroll
            for (int ni = 0; ni < 4; ++ni)
                bf[ni] = *(const s16x8*)&Bs[(wn * 64 + 16 * ni + lrow) * 72 + kc * 32 + quad * 8];
            #pragma unroll
            for (int mi = 0; mi < 4; ++mi)
                #pragma unroll
                for (int ni = 0; ni < 4; ++ni)
                    acc[mi][ni] = MFMA32(af[mi], bf[ni], acc[mi][ni]);
        }
    }

    const int seg = col0 % 384, typ = seg >> 7, h = col0 / 384;
    const size_t bh = (size_t)bb * NH + h;
    const int sl0 = (row0 & 1023) + wm * 64;
    const int cb0 = (seg & 127) + wn * 64;
    float bia[4];
    #pragma unroll
    for (int ni = 0; ni < 4; ++ni) bia[ni] = bias[col0 + wn * 64 + 16 * ni + lrow];

    if (typ < 2) {
        ushort* dst = (typ == 0 ? qo : ko) + bh * SS * 128;
        const float sc = (typ == 0) ? SCALE : 1.f;
        #pragma unroll
        for (int mi = 0; mi < 4; ++mi)
            #pragma unroll
            for (int ni = 0; ni < 4; ++ni)
                #pragma unroll
                for (int reg = 0; reg < 4; ++reg) {
                    int s = sl0 + 16 * mi + quad * 4 + reg;
                    int e = cb0 + 16 * ni + lrow;
                    dst[(size_t)s * 128 + e] = f2bf((acc[mi][ni][reg] + bia[ni]) * sc);
                }
    } else {
        ushort* dst = vto + bh * (size_t)128 * SS;
        #pragma unroll
        for (int mi = 0; mi < 4; ++mi)
            #pragma unroll
            for (int ni = 0; ni < 4; ++ni) {
                int e = cb0 + 16 * ni + lrow;
                int s = sl0 + 16 * mi + quad * 4;
                ushort4 pk;
                pk.x = f2bf(acc[mi][ni][0] + bia[ni]);
                pk.y = f2bf(acc[mi][ni][1] + bia[ni]);
                pk.z = f2bf(acc[mi][ni][2] + bia[ni]);
                pk.w = f2bf(acc[mi][ni][3] + bia[ni]);
                *(ushort4*)&dst[(size_t)e * SS + s] = pk;
            }
    }
}

// ---------------- K2: MFMA flash attention, S-transposed softmax, out-proj fused ----------------
// block = (128 q-rows, h, b), 4 waves x 32 q each (2 groups of 16). MFMA32 only.
static constexpr int KS_LD = 136;
static constexpr int VT_LD = 72;
static constexpr int PS_LD = 72;
static constexpr int WS_LD = 136;   // FIX(r6): was 72 while rows are 128 wide -> row overlap corrupted Wo
static constexpr int OS_LD = 136;
// main loop:  Ks 64*136 + Vt 128*72 + Psw 4*16*72              = 22528 ushorts
// epilogue:   Osl 4*16*136 (aliases Ks exactly) + Ws 128*136   = 26112 ushorts (52224 B, 3 blocks/CU)
static constexpr int SMEM_N = 26112;

__global__ __launch_bounds__(256, 2) void attn_fused_kernel(const ushort* __restrict__ qg_,
                                                            const ushort* __restrict__ kg_,
                                                            const ushort* __restrict__ vg_,
                                                            const ushort* __restrict__ mb,
                                                            const float* __restrict__ wo,
                                                            const float* __restrict__ bo,
                                                            float* __restrict__ out) {
    const int qt = blockIdx.x, h = blockIdx.y, b = blockIdx.z;
    const int s0 = qt * 128;
    const int tid = threadIdx.x;
    const int wave = tid >> 6, lane = tid & 63;
    const int lrow = lane & 15, quad = lane >> 4;

    __shared__ ushort smem[SMEM_N];
    ushort* Ks  = smem;                          // [key][d]
    ushort* Vt  = smem + 64 * KS_LD;             // [d][key]
    ushort* Psw = smem + 64 * KS_LD + 128 * VT_LD + wave * 16 * PS_LD;  // per-wave [q][key]
    ushort* Osl = smem + wave * 16 * OS_LD;      // epilogue: per-wave [q][d], aliases Ks
    ushort* Ws  = smem + 4 * 16 * OS_LD;         // epilogue: Wo[h] bf16 [e][d], stride 136

    const size_t bh = (size_t)(b * NH + h);
    const ushort* qg = qg_ + bh * SS * 128;
    const ushort* kg = kg_ + bh * SS * 128;
    const ushort* vg = vg_ + bh * 128 * SS;
    const ushort* mh = mb + (size_t)h * SS * SS;

    // Q fragments (B-operand of S^T): rows s0+32*wave+16*g+lrow (q pre-scaled)
    s16x8 qf[2][4];
    #pragma unroll
    for (int g = 0; g < 2; ++g) {
        const ushort* qr = qg + (size_t)(s0 + 32 * wave + 16 * g + lrow) * 128 + quad * 8;
        #pragma unroll
        for (int kc = 0; kc < 4; ++kc) qf[g][kc] = *(const s16x8*)(qr + kc * 32);
    }

    // O accumulators in verified C-layout: q=quad*4+reg, dim=16*nb+lane&15
    f32x4 oacc[2][8];
    #pragma unroll
    for (int g = 0; g < 2; ++g)
        #pragma unroll
        for (int nb = 0; nb < 8; ++nb) oacc[g][nb] = (f32x4){0.f, 0.f, 0.f, 0.f};
    float m_run[2] = {-INFINITY, -INFINITY};   // per-lane state for q = lane&15
    float l_run[2] = {0.f, 0.f};

    for (int kt = 0; kt < 16; ++kt) {
        const int t0 = kt * 64;

        // mask loads for this tile (global b64, off the critical path)
        ushort4 mv[2][4];
        #pragma unroll
        for (int g = 0; g < 2; ++g) {
            const ushort* mr = mh + (size_t)(s0 + 32 * wave + 16 * g + lrow) * SS + t0 + quad * 4;
            #pragma unroll
            for (int cb = 0; cb < 4; ++cb) mv[g][cb] = *(const ushort4*)(mr + cb * 16);
        }

        __syncthreads();   // previous iteration's Ks/Vt readers done
        #pragma unroll
        for (int p = 0; p < 4; ++p) {       // K tile 64x128
            int slot = p * 256 + tid;
            int r = slot >> 4, c = (slot & 15) * 8;
            *(s16x8*)&Ks[r * KS_LD + c] = *(const s16x8*)(kg + (size_t)(t0 + r) * 128 + c);
        }
        #pragma unroll
        for (int p = 0; p < 4; ++p) {       // Vt tile 128x64
            int slot = p * 256 + tid;
            int r = slot >> 3, c = (slot & 7) * 8;
            *(s16x8*)&Vt[r * VT_LD + c] = *(const s16x8*)(vg + (size_t)r * SS + t0 + c);
        }
        __syncthreads();

        // ---- S^T = K (q/sqrtD)^T : D[m=key][n=q] ----
        f32x4 sacc[2][4];
        #pragma unroll
        for (int g = 0; g < 2; ++g)
            #pragma unroll
            for (int cb = 0; cb < 4; ++cb) sacc[g][cb] = (f32x4){0.f, 0.f, 0.f, 0.f};
        #pragma unroll
        for (int cb = 0; cb < 4; ++cb) {
            s16x8 kf[4];
            #pragma unroll
            for (int kc = 0; kc < 4; ++kc)
                kf[kc] = *(const s16x8*)&Ks[(16 * cb + lrow) * KS_LD + kc * 32 + quad * 8];
            #pragma unroll
            for (int g = 0; g < 2; ++g)
                #pragma unroll
                for (int kc = 0; kc < 4; ++kc)
                    sacc[g][cb] = MFMA32(kf[kc], qf[g][kc], sacc[g][cb]);
        }

        // ---- per-g: softmax (state in q=lane&15 layout), P->LDS slab, af read ----
        s16x8 af[2][2];
        #pragma unroll
        for (int g = 0; g < 2; ++g) {
            float sv[4][4];
            float tm = -INFINITY;
            #pragma unroll
            for (int cb = 0; cb < 4; ++cb) {
                sv[cb][0] = sacc[g][cb][0] + bf2f(mv[g][cb].x);
                sv[cb][1] = sacc[g][cb][1] + bf2f(mv[g][cb].y);
                sv[cb][2] = sacc[g][cb][2] + bf2f(mv[g][cb].z);
                sv[cb][3] = sacc[g][cb][3] + bf2f(mv[g][cb].w);
                #pragma unroll
                for (int r = 0; r < 4; ++r) tm = fmaxf(tm, sv[cb][r]);
            }
            tm = fmaxf(tm, __shfl_xor(tm, 16));
            tm = fmaxf(tm, __shfl_xor(tm, 32));
            float mn = fmaxf(m_run[g], tm);
            float al = __expf(m_run[g] - mn);
            float rs = 0.f;
            #pragma unroll
            for (int cb = 0; cb < 4; ++cb) {
                float p0 = __expf(sv[cb][0] - mn);
                float p1 = __expf(sv[cb][1] - mn);
                float p2 = __expf(sv[cb][2] - mn);
                float p3 = __expf(sv[cb][3] - mn);
                rs += (p0 + p1) + (p2 + p3);
                ushort4 pw;
                pw.x = f2bf(p0); pw.y = f2bf(p1); pw.z = f2bf(p2); pw.w = f2bf(p3);
                *(ushort4*)&Psw[lrow * PS_LD + 16 * cb + quad * 4] = pw;
            }
            rs += __shfl_xor(rs, 16);
            rs += __shfl_xor(rs, 32);
            l_run[g] = l_run[g] * al + rs;
            m_run[g] = mn;
            // transpose alpha to O's row layout (q = quad*4+reg; state lives in lanes 0-15)
            float alT[4];
            #pragma unroll
            for (int r = 0; r < 4; ++r) alT[r] = __shfl(al, quad * 4 + r);
            #pragma unroll
            for (int nb = 0; nb < 8; ++nb)
                #pragma unroll
                for (int r = 0; r < 4; ++r) oacc[g][nb][r] *= alT[r];
            // read P back as A-operand fragments before g=1 overwrites the slab
            #pragma unroll
            for (int kc = 0; kc < 2; ++kc)
                af[g][kc] = *(const s16x8*)&Psw[lrow * PS_LD + kc * 32 + quad * 8];
        }

        // ---- O += P V ----
        #pragma unroll
        for (int nb = 0; nb < 8; ++nb) {
            #pragma unroll
            for (int kc = 0; kc < 2; ++kc) {
                s16x8 bf = *(const s16x8*)&Vt[(16 * nb + lrow) * VT_LD + kc * 32 + quad * 8];
                #pragma unroll
                for (int g = 0; g < 2; ++g)
                    oacc[g][nb] = MFMA32(af[g][kc], bf, oacc[g][nb]);
            }
        }
    }

    // ---- fused out-projection: out = (O/l) Wo^T + bo ----
    __syncthreads();                       // main-loop LDS readers done
    const float* wbase = wo + (size_t)h * Dh * Dh;
    #pragma unroll
    for (int p = 0; p < 16; ++p) {         // stage Wo[h] 128x128 fp32 -> bf16, stride 136
        int slot = p * 256 + tid;
        int r = slot >> 5, c4 = (slot & 31) << 2;
        float4 wv = *(const float4*)(wbase + (size_t)r * Dh + c4);
        ushort4 pb;
        pb.x = f2bf(wv.x); pb.y = f2bf(wv.y); pb.z = f2bf(wv.z); pb.w = f2bf(wv.w);
        *(ushort4*)&Ws[r * WS_LD + c4] = pb;
    }
    // per-wave: normalized O -> slab (aliases Ks), reread as A-fragments
    s16x8 afo[2][4];
    #pragma unroll
    for (int g = 0; g < 2; ++g) {
        float inv = 1.0f / l_run[g];
        float invT[4];
        #pragma unroll
        for (int r = 0; r < 4; ++r) invT[r] = __shfl(inv, quad * 4 + r);
        #pragma unroll
        for (int nb = 0; nb < 8; ++nb)
            #pragma unroll
            for (int r = 0; r < 4; ++r)
                Osl[(quad * 4 + r) * OS_LD + 16 * nb + lrow] = f2bf(oacc[g][nb][r] * invT[r]);
        #pragma unroll
        for (int kc = 0; kc < 4; ++kc)
            afo[g][kc] = *(const s16x8*)&Osl[lrow * OS_LD + kc * 32 + quad * 8];
    }
    __syncthreads();                       // Ws visible

    const size_t orow0 = (size_t)b * SS + s0 + 32 * wave;
    #pragma unroll
    for (int nb = 0; nb < 8; ++nb) {
        float bia = bo[h * Dh + nb * 16 + lrow];
        f32x4 facc[2];
        facc[0] = (f32x4){0.f, 0.f, 0.f, 0.f};
        facc[1] = (f32x4){0.f, 0.f, 0.f, 0.f};
        #pragma unroll
        for (int kc = 0; kc < 4; ++kc) {
            s16x8 wf = *(const s16x8*)&Ws[(16 * nb + lrow) * WS_LD + kc * 32 + quad * 8];
            facc[0] = MFMA32(afo[0][kc], wf, facc[0]);
            facc[1] = MFMA32(afo[1][kc], wf, facc[1]);
        }
        #pragma unroll
        for (int g = 0; g < 2; ++g)
            #pragma unroll
            for (int reg = 0; reg < 4; ++reg) {
                size_t m = orow0 + 16 * g + quad * 4 + reg;
                out[m * (NH * Dh) + h * Dh + nb * 16 + lrow] = facc[g][reg] + bia;
            }
    }
}

extern "C" void kernel_launch(void* const* d_in, const int* in_sizes, int n_in,
                              void* d_out, int out_size, void* d_ws, size_t ws_size,
                              hipStream_t stream) {
    const float* x     = (const float*)d_in[0];
    const int*   edge  = (const int*)d_in[1];
    const float* w_in  = (const float*)d_in[2];
    const float* b_in  = (const float*)d_in[3];
    const float* w_out = (const float*)d_in[4];
    const float* b_out = (const float*)d_in[5];
    float* out = (float*)d_out;

    float* ws    = (float*)d_ws;
    float* stats = ws;                       // 32
    float* part  = ws + 32;                  // 512
    ushort* mb   = (ushort*)(ws + 1024);     // [4][1024][1024] bf16
    const size_t QSZ = (size_t)NB * NH * SS * 128;
    ushort* qo  = mb + (size_t)NH * SS * SS;
    ushort* ko  = qo + QSZ;
    ushort* vto = ko + QSZ;                  // [b][h][128][s]

    ln_part_kernel<<<256, 256, 0, stream>>>(x, part);
    ln_final_kernel<<<1, 64, 0, stream>>>(part, stats);
    mask_prep_kernel<<<SS * SS / 4 / 256, 256, 0, stream>>>(edge, mb);
    qkv_mfma_kernel<<<dim3(12, 128), 256, 0, stream>>>(x, w_in, b_in, stats, qo, ko, vto);
    attn_fused_kernel<<<dim3(SS / 128, NH, NB), 256, 0, stream>>>(qo, ko, vto, mb, w_out, b_out, out);
}

// Round 8
// 181.486 us; speedup vs baseline: 5.7502x; 1.1816x over previous
//
#include <hip/hip_runtime.h>
#include <math.h>

static constexpr int Dh = 128;
static constexpr int NH = 4;
static constexpr int NB = 16;
static constexpr int SS = 1024;
static constexpr float NEGF = -1e9f;
static constexpr float SCALE = 0.08838834764831843f;  // 1/sqrt(128)

typedef short s16x8 __attribute__((ext_vector_type(8)));
typedef float f32x4 __attribute__((ext_vector_type(4)));

#define MFMA32(a, b, c) __builtin_amdgcn_mfma_f32_16x16x32_bf16(a, b, c, 0, 0, 0)

__device__ inline ushort f2bf(float f) {
    union { float f; unsigned u; } v; v.f = f;
    unsigned r = v.u + 0x7FFFu + ((v.u >> 16) & 1u);
    return (ushort)(r >> 16);
}

// ---------------- K0a: LN partial sums (16 parts per batch) ----------------
__global__ __launch_bounds__(256) void ln_part_kernel(const float* __restrict__ x,
                                                      float* __restrict__ part) {
    const int b = blockIdx.x >> 4, p = blockIdx.x & 15;
    const int tid = threadIdx.x;
    const float4* xb = (const float4*)(x + (size_t)b * SS * Dh) + p * 2048;
    float s = 0.f, ss = 0.f;
    for (int i = tid; i < 2048; i += 256) {
        float4 v = xb[i];
        s  += v.x + v.y + v.z + v.w;
        ss += v.x * v.x + v.y * v.y + v.z * v.z + v.w * v.w;
    }
    __shared__ float r1[256], r2[256];
    r1[tid] = s; r2[tid] = ss;
    __syncthreads();
    for (int off = 128; off > 0; off >>= 1) {
        if (tid < off) { r1[tid] += r1[tid + off]; r2[tid] += r2[tid + off]; }
        __syncthreads();
    }
    if (tid == 0) { part[blockIdx.x * 2] = r1[0]; part[blockIdx.x * 2 + 1] = r2[0]; }
}

// ---------------- K0b: bit mask prep: mbit[h][s][w] (64 keys per word) ----------------
__global__ __launch_bounds__(256) void maskbit_prep_kernel(const int* __restrict__ edge,
                                                           unsigned long long* __restrict__ mbit) {
    const int idx = blockIdx.x * 256 + threadIdx.x;   // < 1024*16
    const int s = idx >> 4, w = idx & 15;
    const int4* ep = (const int4*)(edge + (size_t)s * SS + w * 64);
    unsigned long long m0 = 0, m1 = 0, m2 = 0, m3 = 0;
    #pragma unroll
    for (int j = 0; j < 16; ++j) {
        int4 e = ep[j];
        const int base = j * 4;
        m0 |= (e.x == 1) ? (1ull << (base + 0)) : 0ull;
        m1 |= (e.x == 2) ? (1ull << (base + 0)) : 0ull;
        m2 |= (e.x == 3) ? (1ull << (base + 0)) : 0ull;
        m3 |= (e.x == 4) ? (1ull << (base + 0)) : 0ull;
        m0 |= (e.y == 1) ? (1ull << (base + 1)) : 0ull;
        m1 |= (e.y == 2) ? (1ull << (base + 1)) : 0ull;
        m2 |= (e.y == 3) ? (1ull << (base + 1)) : 0ull;
        m3 |= (e.y == 4) ? (1ull << (base + 1)) : 0ull;
        m0 |= (e.z == 1) ? (1ull << (base + 2)) : 0ull;
        m1 |= (e.z == 2) ? (1ull << (base + 2)) : 0ull;
        m2 |= (e.z == 3) ? (1ull << (base + 2)) : 0ull;
        m3 |= (e.z == 4) ? (1ull << (base + 2)) : 0ull;
        m0 |= (e.w == 1) ? (1ull << (base + 3)) : 0ull;
        m1 |= (e.w == 2) ? (1ull << (base + 3)) : 0ull;
        m2 |= (e.w == 3) ? (1ull << (base + 3)) : 0ull;
        m3 |= (e.w == 4) ? (1ull << (base + 3)) : 0ull;
    }
    mbit[((size_t)0 * SS + s) * 16 + w] = m0;
    mbit[((size_t)1 * SS + s) * 16 + w] = m1;
    mbit[((size_t)2 * SS + s) * 16 + w] = m2;
    mbit[((size_t)3 * SS + s) * 16 + w] = m3;
}

// ---------------- K1: QKV projection, bf16 MFMA (LN fused; coalesced epilogue) ----------------
// q pre-scaled by 1/sqrt(D). q,k row-major bf16 [b][h][s][128]; v transposed [b][h][128][s].
__global__ __launch_bounds__(256) void qkv_mfma_kernel(const float* __restrict__ x,
                                                       const float* __restrict__ w,    // [1536][128]
                                                       const float* __restrict__ bias, // [1536]
                                                       const float* __restrict__ part, // [256][2]
                                                       ushort* __restrict__ qo,
                                                       ushort* __restrict__ ko,
                                                       ushort* __restrict__ vto) {
    __shared__ ushort smem[2 * 128 * 72];     // As/Bs; epilogue alias Rs[128][136] (17408 <= 18432)
    ushort* As = smem;
    ushort* Bs = smem + 128 * 72;
    ushort* Rs = smem;
    const int tid = threadIdx.x, wave = tid >> 6, lane = tid & 63;
    const int lrow = lane & 15, quad = lane >> 4;
    const int wm = wave & 1, wn = wave >> 1;
    const int col0 = blockIdx.x * 128;
    const int row0 = blockIdx.y * 128;
    const int bb = row0 >> 10;

    // LN stats from partials (ln_final folded in; every thread computes the same)
    float s_ = 0.f, ss_ = 0.f;
    #pragma unroll
    for (int p = 0; p < 16; ++p) { s_ += part[(bb * 16 + p) * 2]; ss_ += part[(bb * 16 + p) * 2 + 1]; }
    const float invN = 1.0f / (float)(SS * Dh);
    const float mu = s_ * invN;
    const float rstd = 1.0f / sqrtf(ss_ * invN - mu * mu + 1e-5f);

    f32x4 acc[4][4];
    #pragma unroll
    for (int mi = 0; mi < 4; ++mi)
        #pragma unroll
        for (int ni = 0; ni < 4; ++ni) acc[mi][ni] = (f32x4){0.f, 0.f, 0.f, 0.f};

    for (int kk = 0; kk < 128; kk += 64) {
        if (kk) __syncthreads();
        #pragma unroll
        for (int p = 0; p < 8; ++p) {
            int slot = p * 256 + tid;
            int r = slot >> 4, c4 = (slot & 15) << 2;
            float4 v = *(const float4*)(x + (size_t)(row0 + r) * Dh + kk + c4);
            ushort4 pa;
            pa.x = f2bf((v.x - mu) * rstd); pa.y = f2bf((v.y - mu) * rstd);
            pa.z = f2bf((v.z - mu) * rstd); pa.w = f2bf((v.w - mu) * rstd);
            *(ushort4*)&As[r * 72 + c4] = pa;
            float4 wv = *(const float4*)(w + (size_t)(col0 + r) * Dh + kk + c4);
            ushort4 pb;
            pb.x = f2bf(wv.x); pb.y = f2bf(wv.y); pb.z = f2bf(wv.z); pb.w = f2bf(wv.w);
            *(ushort4*)&Bs[r * 72 + c4] = pb;
        }
        __syncthreads();
        #pragma unroll
        for (int kc = 0; kc < 2; ++kc) {
            s16x8 af[4], bf[4];
            #pragma unroll
            for (int mi = 0; mi < 4; ++mi)
                af[mi] = *(const s16x8*)&As[(wm * 64 + 16 * mi + lrow) * 72 + kc * 32 + quad * 8];
            #pragma unroll
            for (int ni = 0; ni < 4; ++ni)
                bf[ni] = *(const s16x8*)&Bs[(wn * 64 + 16 * ni + lrow) * 72 + kc * 32 + quad * 8];
            #pragma unroll
            for (int mi = 0; mi < 4; ++mi)
                #pragma unroll
                for (int ni = 0; ni < 4; ++ni)
                    acc[mi][ni] = MFMA32(af[mi], bf[ni], acc[mi][ni]);
        }
    }

    const int seg = col0 % 384, typ = seg >> 7, h = col0 / 384;
    const size_t bh = (size_t)bb * NH + h;
    const int sl_blk = row0 & 1023;
    float bia[4];
    #pragma unroll
    for (int ni = 0; ni < 4; ++ni) bia[ni] = bias[col0 + wn * 64 + 16 * ni + lrow];
    const float sc = (typ == 0) ? SCALE : 1.f;

    __syncthreads();    // As/Bs fragment readers done; reuse as Rs
    if (typ < 2) {
        // Rs[s_local][e]
        #pragma unroll
        for (int mi = 0; mi < 4; ++mi)
            #pragma unroll
            for (int ni = 0; ni < 4; ++ni)
                #pragma unroll
                for (int reg = 0; reg < 4; ++reg)
                    Rs[(wm * 64 + 16 * mi + quad * 4 + reg) * 136 + wn * 64 + 16 * ni + lrow]
                        = f2bf((acc[mi][ni][reg] + bia[ni]) * sc);
    } else {
        // Rs[e][s_local], vectorized along s (reg-contiguous)
        #pragma unroll
        for (int mi = 0; mi < 4; ++mi)
            #pragma unroll
            for (int ni = 0; ni < 4; ++ni) {
                ushort4 pk;
                pk.x = f2bf(acc[mi][ni][0] + bia[ni]);
                pk.y = f2bf(acc[mi][ni][1] + bia[ni]);
                pk.z = f2bf(acc[mi][ni][2] + bia[ni]);
                pk.w = f2bf(acc[mi][ni][3] + bia[ni]);
                *(ushort4*)&Rs[(wn * 64 + 16 * ni + lrow) * 136 + wm * 64 + 16 * mi + quad * 4] = pk;
            }
    }
    __syncthreads();

    ushort* dstb;
    int pitch;
    if (typ == 0)      { dstb = qo  + bh * SS * 128 + (size_t)sl_blk * 128; pitch = 128; }
    else if (typ == 1) { dstb = ko  + bh * SS * 128 + (size_t)sl_blk * 128; pitch = 128; }
    else               { dstb = vto + bh * (size_t)128 * SS + sl_blk;       pitch = SS;  }
    #pragma unroll
    for (int p = 0; p < 8; ++p) {
        int slot = p * 256 + tid;
        int r = slot >> 4, c8 = (slot & 15) * 8;
        *(s16x8*)&dstb[(size_t)r * pitch + c8] = *(const s16x8*)&Rs[r * 136 + c8];
    }
}

// ---------------- K2: MFMA flash attention, bit-mask, reg-prefetch, out-proj fused ----------------
static constexpr int KS_LD = 136;
static constexpr int VT_LD = 72;
static constexpr int PS_LD = 72;
static constexpr int WS_LD = 136;
static constexpr int OS_LD = 136;
static constexpr int SMEM_N = 26112;   // 52224 B

__global__ __launch_bounds__(256, 2) void attn_fused_kernel(const ushort* __restrict__ qg_,
                                                            const ushort* __restrict__ kg_,
                                                            const ushort* __restrict__ vg_,
                                                            const unsigned long long* __restrict__ mbit,
                                                            const float* __restrict__ wo,
                                                            const float* __restrict__ bo,
                                                            float* __restrict__ out) {
    const int qt = blockIdx.x, h = blockIdx.y, b = blockIdx.z;
    const int s0 = qt * 128;
    const int tid = threadIdx.x;
    const int wave = tid >> 6, lane = tid & 63;
    const int lrow = lane & 15, quad = lane >> 4;

    __shared__ ushort smem[SMEM_N];
    ushort* Ks  = smem;                          // [key][d]
    ushort* Vt  = smem + 64 * KS_LD;             // [d][key]
    ushort* Psw = smem + 64 * KS_LD + 128 * VT_LD + wave * 16 * PS_LD;  // per-wave [q][key]
    ushort* Osl = smem + wave * 16 * OS_LD;      // epilogue: per-wave [q][d], aliases Ks
    ushort* Ws  = smem + 4 * 16 * OS_LD;         // epilogue: Wo[h] bf16 [e][d], stride 136

    const size_t bh = (size_t)(b * NH + h);
    const ushort* qg = qg_ + bh * SS * 128;
    const ushort* kg = kg_ + bh * SS * 128;
    const ushort* vg = vg_ + bh * 128 * SS;
    const unsigned long long* mrow0 = mbit + ((size_t)h * SS + (s0 + 32 * wave + lrow)) * 16;
    const unsigned long long* mrow1 = mrow0 + 16 * 16;   // +16 rows

    // Q fragments (B-operand of S^T)
    s16x8 qf[2][4];
    #pragma unroll
    for (int g = 0; g < 2; ++g) {
        const ushort* qr = qg + (size_t)(s0 + 32 * wave + 16 * g + lrow) * 128 + quad * 8;
        #pragma unroll
        for (int kc = 0; kc < 4; ++kc) qf[g][kc] = *(const s16x8*)(qr + kc * 32);
    }

    // staging prefetch registers (tile kt=0)
    s16x8 kreg[4], vreg[4];
    #pragma unroll
    for (int p = 0; p < 4; ++p) {
        int slot = p * 256 + tid;
        int r = slot >> 4, c = (slot & 15) * 8;
        kreg[p] = *(const s16x8*)(kg + (size_t)r * 128 + c);
    }
    #pragma unroll
    for (int p = 0; p < 4; ++p) {
        int slot = p * 256 + tid;
        int r = slot >> 3, c = (slot & 7) * 8;
        vreg[p] = *(const s16x8*)(vg + (size_t)r * SS + c);
    }

    f32x4 oacc[2][8];
    #pragma unroll
    for (int g = 0; g < 2; ++g)
        #pragma unroll
        for (int nb = 0; nb < 8; ++nb) oacc[g][nb] = (f32x4){0.f, 0.f, 0.f, 0.f};
    float m_run[2] = {-INFINITY, -INFINITY};
    float l_run[2] = {0.f, 0.f};

    for (int kt = 0; kt < 16; ++kt) {
        const int t0 = kt * 64;
        unsigned long long mw0 = mrow0[kt];
        unsigned long long mw1 = mrow1[kt];

        __syncthreads();   // previous iteration's Ks/Vt readers done
        #pragma unroll
        for (int p = 0; p < 4; ++p) {
            int slot = p * 256 + tid;
            int r = slot >> 4, c = (slot & 15) * 8;
            *(s16x8*)&Ks[r * KS_LD + c] = kreg[p];
        }
        #pragma unroll
        for (int p = 0; p < 4; ++p) {
            int slot = p * 256 + tid;
            int r = slot >> 3, c = (slot & 7) * 8;
            *(s16x8*)&Vt[r * VT_LD + c] = vreg[p];
        }
        __syncthreads();

        // prefetch next tile into regs (overlaps with compute below)
        if (kt < 15) {
            const int t1 = t0 + 64;
            #pragma unroll
            for (int p = 0; p < 4; ++p) {
                int slot = p * 256 + tid;
                int r = slot >> 4, c = (slot & 15) * 8;
                kreg[p] = *(const s16x8*)(kg + (size_t)(t1 + r) * 128 + c);
            }
            #pragma unroll
            for (int p = 0; p < 4; ++p) {
                int slot = p * 256 + tid;
                int r = slot >> 3, c = (slot & 7) * 8;
                vreg[p] = *(const s16x8*)(vg + (size_t)r * SS + t1 + c);
            }
        }

        // ---- S^T = K (q/sqrtD)^T : D[m=key][n=q] ----
        f32x4 sacc[2][4];
        #pragma unroll
        for (int g = 0; g < 2; ++g)
            #pragma unroll
            for (int cb = 0; cb < 4; ++cb) sacc[g][cb] = (f32x4){0.f, 0.f, 0.f, 0.f};
        #pragma unroll
        for (int cb = 0; cb < 4; ++cb) {
            s16x8 kf[4];
            #pragma unroll
            for (int kc = 0; kc < 4; ++kc)
                kf[kc] = *(const s16x8*)&Ks[(16 * cb + lrow) * KS_LD + kc * 32 + quad * 8];
            #pragma unroll
            for (int g = 0; g < 2; ++g)
                #pragma unroll
                for (int kc = 0; kc < 4; ++kc)
                    sacc[g][cb] = MFMA32(kf[kc], qf[g][kc], sacc[g][cb]);
        }

        // ---- per-g softmax: bit-select mask, per-lane state (q = lane&15) ----
        s16x8 af[2][2];
        #pragma unroll
        for (int g = 0; g < 2; ++g) {
            const unsigned long long mw = g ? mw1 : mw0;
            float sv[4][4];
            float tm = -INFINITY;
            #pragma unroll
            for (int cb = 0; cb < 4; ++cb) {
                unsigned nib = (unsigned)(mw >> (16 * cb + quad * 4)) & 0xFu;
                #pragma unroll
                for (int r = 0; r < 4; ++r) {
                    sv[cb][r] = (nib & (1u << r)) ? sacc[g][cb][r] : NEGF;
                    tm = fmaxf(tm, sv[cb][r]);
                }
            }
            tm = fmaxf(tm, __shfl_xor(tm, 16));
            tm = fmaxf(tm, __shfl_xor(tm, 32));
            float mn = fmaxf(m_run[g], tm);
            float al = __expf(m_run[g] - mn);
            float rs = 0.f;
            #pragma unroll
            for (int cb = 0; cb < 4; ++cb) {
                float p0 = __expf(sv[cb][0] - mn);
                float p1 = __expf(sv[cb][1] - mn);
                float p2 = __expf(sv[cb][2] - mn);
                float p3 = __expf(sv[cb][3] - mn);
                rs += (p0 + p1) + (p2 + p3);
                ushort4 pw;
                pw.x = f2bf(p0); pw.y = f2bf(p1); pw.z = f2bf(p2); pw.w = f2bf(p3);
                *(ushort4*)&Psw[lrow * PS_LD + 16 * cb + quad * 4] = pw;
            }
            rs += __shfl_xor(rs, 16);
            rs += __shfl_xor(rs, 32);
            l_run[g] = l_run[g] * al + rs;
            m_run[g] = mn;
            float alT[4];
            #pragma unroll
            for (int r = 0; r < 4; ++r) alT[r] = __shfl(al, quad * 4 + r);
            #pragma unroll
            for (int nb = 0; nb < 8; ++nb)
                #pragma unroll
                for (int r = 0; r < 4; ++r) oacc[g][nb][r] *= alT[r];
            #pragma unroll
            for (int kc = 0; kc < 2; ++kc)
                af[g][kc] = *(const s16x8*)&Psw[lrow * PS_LD + kc * 32 + quad * 8];
        }

        // ---- O += P V ----
        #pragma unroll
        for (int nb = 0; nb < 8; ++nb) {
            #pragma unroll
            for (int kc = 0; kc < 2; ++kc) {
                s16x8 bf = *(const s16x8*)&Vt[(16 * nb + lrow) * VT_LD + kc * 32 + quad * 8];
                #pragma unroll
                for (int g = 0; g < 2; ++g)
                    oacc[g][nb] = MFMA32(af[g][kc], bf, oacc[g][nb]);
            }
        }
    }

    // ---- fused out-projection: out = (O/l) Wo^T + bo ----
    __syncthreads();
    const float* wbase = wo + (size_t)h * Dh * Dh;
    #pragma unroll
    for (int p = 0; p < 16; ++p) {
        int slot = p * 256 + tid;
        int r = slot >> 5, c4 = (slot & 31) << 2;
        float4 wv = *(const float4*)(wbase + (size_t)r * Dh + c4);
        ushort4 pb;
        pb.x = f2bf(wv.x); pb.y = f2bf(wv.y); pb.z = f2bf(wv.z); pb.w = f2bf(wv.w);
        *(ushort4*)&Ws[r * WS_LD + c4] = pb;
    }
    s16x8 afo[2][4];
    #pragma unroll
    for (int g = 0; g < 2; ++g) {
        float inv = 1.0f / l_run[g];
        float invT[4];
        #pragma unroll
        for (int r = 0; r < 4; ++r) invT[r] = __shfl(inv, quad * 4 + r);
        #pragma unroll
        for (int nb = 0; nb < 8; ++nb)
            #pragma unroll
            for (int r = 0; r < 4; ++r)
                Osl[(quad * 4 + r) * OS_LD + 16 * nb + lrow] = f2bf(oacc[g][nb][r] * invT[r]);
        #pragma unroll
        for (int kc = 0; kc < 4; ++kc)
            afo[g][kc] = *(const s16x8*)&Osl[lrow * OS_LD + kc * 32 + quad * 8];
    }
    __syncthreads();

    const size_t orow0 = (size_t)b * SS + s0 + 32 * wave;
    #pragma unroll
    for (int nb = 0; nb < 8; ++nb) {
        float bia = bo[h * Dh + nb * 16 + lrow];
        f32x4 facc[2];
        facc[0] = (f32x4){0.f, 0.f, 0.f, 0.f};
        facc[1] = (f32x4){0.f, 0.f, 0.f, 0.f};
        #pragma unroll
        for (int kc = 0; kc < 4; ++kc) {
            s16x8 wf = *(const s16x8*)&Ws[(16 * nb + lrow) * WS_LD + kc * 32 + quad * 8];
            facc[0] = MFMA32(afo[0][kc], wf, facc[0]);
            facc[1] = MFMA32(afo[1][kc], wf, facc[1]);
        }
        #pragma unroll
        for (int g = 0; g < 2; ++g)
            #pragma unroll
            for (int reg = 0; reg < 4; ++reg) {
                size_t m = orow0 + 16 * g + quad * 4 + reg;
                out[m * (NH * Dh) + h * Dh + nb * 16 + lrow] = facc[g][reg] + bia;
            }
    }
}

extern "C" void kernel_launch(void* const* d_in, const int* in_sizes, int n_in,
                              void* d_out, int out_size, void* d_ws, size_t ws_size,
                              hipStream_t stream) {
    const float* x     = (const float*)d_in[0];
    const int*   edge  = (const int*)d_in[1];
    const float* w_in  = (const float*)d_in[2];
    const float* b_in  = (const float*)d_in[3];
    const float* w_out = (const float*)d_in[4];
    const float* b_out = (const float*)d_in[5];
    float* out = (float*)d_out;

    float* ws   = (float*)d_ws;
    float* part = ws;                                     // 512 floats
    unsigned long long* mbit = (unsigned long long*)(ws + 1024);   // [4][1024][16] u64 = 512 KB
    ushort* qo  = (ushort*)(mbit + (size_t)NH * SS * 16);
    const size_t QSZ = (size_t)NB * NH * SS * 128;
    ushort* ko  = qo + QSZ;
    ushort* vto = ko + QSZ;                               // [b][h][128][s]

    ln_part_kernel<<<256, 256, 0, stream>>>(x, part);
    maskbit_prep_kernel<<<SS * 16 / 256, 256, 0, stream>>>(edge, mbit);
    qkv_mfma_kernel<<<dim3(12, 128), 256, 0, stream>>>(x, w_in, b_in, part, qo, ko, vto);
    attn_fused_kernel<<<dim3(SS / 128, NH, NB), 256, 0, stream>>>(qo, ko, vto, mbit, w_out, b_out, out);
}

// Round 9
// 174.802 us; speedup vs baseline: 5.9701x; 1.0382x over previous
//
#include <hip/hip_runtime.h>
#include <math.h>

static constexpr int Dh = 128;
static constexpr int NH = 4;
static constexpr int NB = 16;
static constexpr int SS = 1024;
static constexpr float NEGF = -1e9f;
static constexpr float SCALE = 0.08838834764831843f;  // 1/sqrt(128)

typedef short s16x8 __attribute__((ext_vector_type(8)));
typedef short s16x4 __attribute__((ext_vector_type(4)));
typedef float f32x4 __attribute__((ext_vector_type(4)));

#define MFMA32(a, b, c) __builtin_amdgcn_mfma_f32_16x16x32_bf16(a, b, c, 0, 0, 0)
// K=16 bf16 MFMA: layouts HW-validated by the r5-vs-r6 byte-identical-absmax A/B.
#define MFMA16(a, b, c) __builtin_amdgcn_mfma_f32_16x16x16bf16_1k(a, b, c, 0, 0, 0)

__device__ inline ushort f2bf(float f) {
    union { float f; unsigned u; } v; v.f = f;
    unsigned r = v.u + 0x7FFFu + ((v.u >> 16) & 1u);
    return (ushort)(r >> 16);
}

// ---------------- K0: fused LN partial sums + bit-mask prep ----------------
__global__ __launch_bounds__(256) void ln_mask_kernel(const float* __restrict__ x,
                                                      float* __restrict__ part,
                                                      const int* __restrict__ edge,
                                                      unsigned long long* __restrict__ mbit) {
    const int b = blockIdx.x >> 4, p = blockIdx.x & 15;
    const int tid = threadIdx.x;
    const float4* xb = (const float4*)(x + (size_t)b * SS * Dh) + p * 2048;
    float s = 0.f, ss = 0.f;
    for (int i = tid; i < 2048; i += 256) {
        float4 v = xb[i];
        s  += v.x + v.y + v.z + v.w;
        ss += v.x * v.x + v.y * v.y + v.z * v.z + v.w * v.w;
    }
    __shared__ float r1[256], r2[256];
    r1[tid] = s; r2[tid] = ss;
    __syncthreads();
    for (int off = 128; off > 0; off >>= 1) {
        if (tid < off) { r1[tid] += r1[tid + off]; r2[tid] += r2[tid + off]; }
        __syncthreads();
    }
    if (tid == 0) { part[blockIdx.x * 2] = r1[0]; part[blockIdx.x * 2 + 1] = r2[0]; }

    // mask prep on first 64 blocks (independent work, same dispatch)
    if (blockIdx.x < 64) {
        const int idx = blockIdx.x * 256 + tid;   // < 1024*16
        const int sr = idx >> 4, w = idx & 15;
        const int4* ep = (const int4*)(edge + (size_t)sr * SS + w * 64);
        unsigned long long m0 = 0, m1 = 0, m2 = 0, m3 = 0;
        #pragma unroll
        for (int j = 0; j < 16; ++j) {
            int4 e = ep[j];
            const int base = j * 4;
            m0 |= (e.x == 1) ? (1ull << (base + 0)) : 0ull;
            m1 |= (e.x == 2) ? (1ull << (base + 0)) : 0ull;
            m2 |= (e.x == 3) ? (1ull << (base + 0)) : 0ull;
            m3 |= (e.x == 4) ? (1ull << (base + 0)) : 0ull;
            m0 |= (e.y == 1) ? (1ull << (base + 1)) : 0ull;
            m1 |= (e.y == 2) ? (1ull << (base + 1)) : 0ull;
            m2 |= (e.y == 3) ? (1ull << (base + 1)) : 0ull;
            m3 |= (e.y == 4) ? (1ull << (base + 1)) : 0ull;
            m0 |= (e.z == 1) ? (1ull << (base + 2)) : 0ull;
            m1 |= (e.z == 2) ? (1ull << (base + 2)) : 0ull;
            m2 |= (e.z == 3) ? (1ull << (base + 2)) : 0ull;
            m3 |= (e.z == 4) ? (1ull << (base + 2)) : 0ull;
            m0 |= (e.w == 1) ? (1ull << (base + 3)) : 0ull;
            m1 |= (e.w == 2) ? (1ull << (base + 3)) : 0ull;
            m2 |= (e.w == 3) ? (1ull << (base + 3)) : 0ull;
            m3 |= (e.w == 4) ? (1ull << (base + 3)) : 0ull;
        }
        mbit[((size_t)0 * SS + sr) * 16 + w] = m0;
        mbit[((size_t)1 * SS + sr) * 16 + w] = m1;
        mbit[((size_t)2 * SS + sr) * 16 + w] = m2;
        mbit[((size_t)3 * SS + sr) * 16 + w] = m3;
    }
}

// ---------------- K1: QKV projection, bf16 MFMA (LN fused; coalesced epilogue) ----------------
__global__ __launch_bounds__(256) void qkv_mfma_kernel(const float* __restrict__ x,
                                                       const float* __restrict__ w,    // [1536][128]
                                                       const float* __restrict__ bias, // [1536]
                                                       const float* __restrict__ part, // [256][2]
                                                       ushort* __restrict__ qo,
                                                       ushort* __restrict__ ko,
                                                       ushort* __restrict__ vto) {
    __shared__ ushort smem[2 * 128 * 72];     // As/Bs; epilogue alias Rs[128][136]
    ushort* As = smem;
    ushort* Bs = smem + 128 * 72;
    ushort* Rs = smem;
    const int tid = threadIdx.x, wave = tid >> 6, lane = tid & 63;
    const int lrow = lane & 15, quad = lane >> 4;
    const int wm = wave & 1, wn = wave >> 1;
    const int col0 = blockIdx.x * 128;
    const int row0 = blockIdx.y * 128;
    const int bb = row0 >> 10;

    float s_ = 0.f, ss_ = 0.f;
    #pragma unroll
    for (int p = 0; p < 16; ++p) { s_ += part[(bb * 16 + p) * 2]; ss_ += part[(bb * 16 + p) * 2 + 1]; }
    const float invN = 1.0f / (float)(SS * Dh);
    const float mu = s_ * invN;
    const float rstd = 1.0f / sqrtf(ss_ * invN - mu * mu + 1e-5f);

    f32x4 acc[4][4];
    #pragma unroll
    for (int mi = 0; mi < 4; ++mi)
        #pragma unroll
        for (int ni = 0; ni < 4; ++ni) acc[mi][ni] = (f32x4){0.f, 0.f, 0.f, 0.f};

    for (int kk = 0; kk < 128; kk += 64) {
        if (kk) __syncthreads();
        #pragma unroll
        for (int p = 0; p < 8; ++p) {
            int slot = p * 256 + tid;
            int r = slot >> 4, c4 = (slot & 15) << 2;
            float4 v = *(const float4*)(x + (size_t)(row0 + r) * Dh + kk + c4);
            ushort4 pa;
            pa.x = f2bf((v.x - mu) * rstd); pa.y = f2bf((v.y - mu) * rstd);
            pa.z = f2bf((v.z - mu) * rstd); pa.w = f2bf((v.w - mu) * rstd);
            *(ushort4*)&As[r * 72 + c4] = pa;
            float4 wv = *(const float4*)(w + (size_t)(col0 + r) * Dh + kk + c4);
            ushort4 pb;
            pb.x = f2bf(wv.x); pb.y = f2bf(wv.y); pb.z = f2bf(wv.z); pb.w = f2bf(wv.w);
            *(ushort4*)&Bs[r * 72 + c4] = pb;
        }
        __syncthreads();
        #pragma unroll
        for (int kc = 0; kc < 2; ++kc) {
            s16x8 af[4], bf[4];
            #pragma unroll
            for (int mi = 0; mi < 4; ++mi)
                af[mi] = *(const s16x8*)&As[(wm * 64 + 16 * mi + lrow) * 72 + kc * 32 + quad * 8];
            #pragma unroll
            for (int ni = 0; ni < 4; ++ni)
                bf[ni] = *(const s16x8*)&Bs[(wn * 64 + 16 * ni + lrow) * 72 + kc * 32 + quad * 8];
            #pragma unroll
            for (int mi = 0; mi < 4; ++mi)
                #pragma unroll
                for (int ni = 0; ni < 4; ++ni)
                    acc[mi][ni] = MFMA32(af[mi], bf[ni], acc[mi][ni]);
        }
    }

    const int seg = col0 % 384, typ = seg >> 7, h = col0 / 384;
    const size_t bh = (size_t)bb * NH + h;
    const int sl_blk = row0 & 1023;
    float bia[4];
    #pragma unroll
    for (int ni = 0; ni < 4; ++ni) bia[ni] = bias[col0 + wn * 64 + 16 * ni + lrow];
    const float sc = (typ == 0) ? SCALE : 1.f;

    __syncthreads();
    if (typ < 2) {
        #pragma unroll
        for (int mi = 0; mi < 4; ++mi)
            #pragma unroll
            for (int ni = 0; ni < 4; ++ni)
                #pragma unroll
                for (int reg = 0; reg < 4; ++reg)
                    Rs[(wm * 64 + 16 * mi + quad * 4 + reg) * 136 + wn * 64 + 16 * ni + lrow]
                        = f2bf((acc[mi][ni][reg] + bia[ni]) * sc);
    } else {
        #pragma unroll
        for (int mi = 0; mi < 4; ++mi)
            #pragma unroll
            for (int ni = 0; ni < 4; ++ni) {
                ushort4 pk;
                pk.x = f2bf(acc[mi][ni][0] + bia[ni]);
                pk.y = f2bf(acc[mi][ni][1] + bia[ni]);
                pk.z = f2bf(acc[mi][ni][2] + bia[ni]);
                pk.w = f2bf(acc[mi][ni][3] + bia[ni]);
                *(ushort4*)&Rs[(wn * 64 + 16 * ni + lrow) * 136 + wm * 64 + 16 * mi + quad * 4] = pk;
            }
    }
    __syncthreads();

    ushort* dstb;
    int pitch;
    if (typ == 0)      { dstb = qo  + bh * SS * 128 + (size_t)sl_blk * 128; pitch = 128; }
    else if (typ == 1) { dstb = ko  + bh * SS * 128 + (size_t)sl_blk * 128; pitch = 128; }
    else               { dstb = vto + bh * (size_t)128 * SS + sl_blk;       pitch = SS;  }
    #pragma unroll
    for (int p = 0; p < 8; ++p) {
        int slot = p * 256 + tid;
        int r = slot >> 4, c8 = (slot & 15) * 8;
        *(s16x8*)&dstb[(size_t)r * pitch + c8] = *(const s16x8*)&Rs[r * 136 + c8];
    }
}

// ---------------- K2: MFMA flash attention; S^T softmax; reg-P MFMA16 PV; fused out-proj ----------------
static constexpr int KS_LD = 136;
static constexpr int VT_LD = 72;
static constexpr int WS_LD = 136;
static constexpr int OS_LD = 136;
static constexpr int SMEM_N = 26112;   // 52224 B (main: Ks 64*136 + Vt 128*72; epi: Osl 4*16*136 + Ws 128*136)

__global__ __launch_bounds__(256, 2) void attn_fused_kernel(const ushort* __restrict__ qg_,
                                                            const ushort* __restrict__ kg_,
                                                            const ushort* __restrict__ vg_,
                                                            const unsigned long long* __restrict__ mbit,
                                                            const float* __restrict__ wo,
                                                            const float* __restrict__ bo,
                                                            float* __restrict__ out) {
    // XCD swizzle: blockIdx.x = (b,h) so all 8 q-tiles of a (b,h) share id%8 -> same XCD L2
    const int bhi = blockIdx.x, qt = blockIdx.y;
    const int b = bhi >> 2, h = bhi & 3;
    const int s0 = qt * 128;
    const int tid = threadIdx.x;
    const int wave = tid >> 6, lane = tid & 63;
    const int lrow = lane & 15, quad = lane >> 4;

    __shared__ ushort smem[SMEM_N];
    ushort* Ks  = smem;                          // [key][d]
    ushort* Vt  = smem + 64 * KS_LD;             // [d][key]
    ushort* Osl = smem + wave * 16 * OS_LD;      // epilogue: per-wave [q][d], aliases Ks
    ushort* Ws  = smem + 4 * 16 * OS_LD;         // epilogue: Wo[h] bf16 [e][d]

    const size_t bh = (size_t)(b * NH + h);
    const ushort* qg = qg_ + bh * SS * 128;
    const ushort* kg = kg_ + bh * SS * 128;
    const ushort* vg = vg_ + bh * 128 * SS;
    const unsigned long long* mrow0 = mbit + ((size_t)h * SS + (s0 + 32 * wave + lrow)) * 16;
    const unsigned long long* mrow1 = mrow0 + 16 * 16;

    // Q fragments (B-operand of S^T MFMA32): n=q=lane&15, k=kc*32+quad*8+j
    s16x8 qf[2][4];
    #pragma unroll
    for (int g = 0; g < 2; ++g) {
        const ushort* qr = qg + (size_t)(s0 + 32 * wave + 16 * g + lrow) * 128 + quad * 8;
        #pragma unroll
        for (int kc = 0; kc < 4; ++kc) qf[g][kc] = *(const s16x8*)(qr + kc * 32);
    }

    // staging prefetch registers (tile kt=0)
    s16x8 kreg[4], vreg[4];
    #pragma unroll
    for (int p = 0; p < 4; ++p) {
        int slot = p * 256 + tid;
        int r = slot >> 4, c = (slot & 15) * 8;
        kreg[p] = *(const s16x8*)(kg + (size_t)r * 128 + c);
    }
    #pragma unroll
    for (int p = 0; p < 4; ++p) {
        int slot = p * 256 + tid;
        int r = slot >> 3, c = (slot & 7) * 8;
        vreg[p] = *(const s16x8*)(vg + (size_t)r * SS + c);
    }

    // O^T accumulators: D[m=d][n=q]: q = lane&15 (aligned with softmax state!), d = 16*nb+quad*4+reg
    f32x4 oacc[2][8];
    #pragma unroll
    for (int g = 0; g < 2; ++g)
        #pragma unroll
        for (int nb = 0; nb < 8; ++nb) oacc[g][nb] = (f32x4){0.f, 0.f, 0.f, 0.f};
    float m_run[2] = {-INFINITY, -INFINITY};
    float l_run[2] = {0.f, 0.f};

    for (int kt = 0; kt < 16; ++kt) {
        const int t0 = kt * 64;
        unsigned long long mw0 = mrow0[kt];
        unsigned long long mw1 = mrow1[kt];

        __syncthreads();
        #pragma unroll
        for (int p = 0; p < 4; ++p) {
            int slot = p * 256 + tid;
            int r = slot >> 4, c = (slot & 15) * 8;
            *(s16x8*)&Ks[r * KS_LD + c] = kreg[p];
        }
        #pragma unroll
        for (int p = 0; p < 4; ++p) {
            int slot = p * 256 + tid;
            int r = slot >> 3, c = (slot & 7) * 8;
            *(s16x8*)&Vt[r * VT_LD + c] = vreg[p];
        }
        __syncthreads();

        if (kt < 15) {
            const int t1 = t0 + 64;
            #pragma unroll
            for (int p = 0; p < 4; ++p) {
                int slot = p * 256 + tid;
                int r = slot >> 4, c = (slot & 15) * 8;
                kreg[p] = *(const s16x8*)(kg + (size_t)(t1 + r) * 128 + c);
            }
            #pragma unroll
            for (int p = 0; p < 4; ++p) {
                int slot = p * 256 + tid;
                int r = slot >> 3, c = (slot & 7) * 8;
                vreg[p] = *(const s16x8*)(vg + (size_t)r * SS + t1 + c);
            }
        }

        // ---- S^T = K (q/sqrtD)^T : D[m=key][n=q]; key = 16*cb+quad*4+reg, q = lane&15 ----
        f32x4 sacc[2][4];
        #pragma unroll
        for (int g = 0; g < 2; ++g)
            #pragma unroll
            for (int cb = 0; cb < 4; ++cb) sacc[g][cb] = (f32x4){0.f, 0.f, 0.f, 0.f};
        #pragma unroll
        for (int cb = 0; cb < 4; ++cb) {
            s16x8 kf[4];
            #pragma unroll
            for (int kc = 0; kc < 4; ++kc)
                kf[kc] = *(const s16x8*)&Ks[(16 * cb + lrow) * KS_LD + kc * 32 + quad * 8];
            #pragma unroll
            for (int g = 0; g < 2; ++g)
                #pragma unroll
                for (int kc = 0; kc < 4; ++kc)
                    sacc[g][cb] = MFMA32(kf[kc], qf[g][kc], sacc[g][cb]);
        }

        // ---- softmax (per-lane state, q=lane&15) + pf pack (sacc layout == MFMA16 B-operand!) ----
        s16x4 pf[2][4];
        #pragma unroll
        for (int g = 0; g < 2; ++g) {
            const unsigned long long mw = g ? mw1 : mw0;
            float sv[4][4];
            float tm = -INFINITY;
            #pragma unroll
            for (int cb = 0; cb < 4; ++cb) {
                unsigned nib = (unsigned)(mw >> (16 * cb + quad * 4)) & 0xFu;
                #pragma unroll
                for (int r = 0; r < 4; ++r) {
                    sv[cb][r] = (nib & (1u << r)) ? sacc[g][cb][r] : NEGF;
                    tm = fmaxf(tm, sv[cb][r]);
                }
            }
            tm = fmaxf(tm, __shfl_xor(tm, 16));
            tm = fmaxf(tm, __shfl_xor(tm, 32));
            float mn = fmaxf(m_run[g], tm);
            float al = __expf(m_run[g] - mn);
            float rs = 0.f;
            #pragma unroll
            for (int cb = 0; cb < 4; ++cb) {
                float p0 = __expf(sv[cb][0] - mn);
                float p1 = __expf(sv[cb][1] - mn);
                float p2 = __expf(sv[cb][2] - mn);
                float p3 = __expf(sv[cb][3] - mn);
                rs += (p0 + p1) + (p2 + p3);
                s16x4 pk;
                pk[0] = (short)f2bf(p0); pk[1] = (short)f2bf(p1);
                pk[2] = (short)f2bf(p2); pk[3] = (short)f2bf(p3);
                pf[g][cb] = pk;
            }
            rs += __shfl_xor(rs, 16);
            rs += __shfl_xor(rs, 32);
            l_run[g] = l_run[g] * al + rs;
            m_run[g] = mn;
            // O^T rescale: q = lane&15 -> per-lane al applies directly, no transpose
            #pragma unroll
            for (int nb = 0; nb < 8; ++nb)
                #pragma unroll
                for (int r = 0; r < 4; ++r) oacc[g][nb][r] *= al;
        }

        // ---- O^T += V^T P^T : MFMA16, A = V^T frag (b64 LDS), B = pf (registers) ----
        #pragma unroll
        for (int nb = 0; nb < 8; ++nb) {
            #pragma unroll
            for (int kb = 0; kb < 4; ++kb) {
                s16x4 vf = *(const s16x4*)&Vt[(16 * nb + lrow) * VT_LD + kb * 16 + quad * 4];
                #pragma unroll
                for (int g = 0; g < 2; ++g)
                    oacc[g][nb] = MFMA16(vf, pf[g][kb], oacc[g][nb]);
            }
        }
    }

    // ---- fused out-projection: out = (O/l) Wo^T + bo ----
    __syncthreads();
    const float* wbase = wo + (size_t)h * Dh * Dh;
    #pragma unroll
    for (int p = 0; p < 16; ++p) {
        int slot = p * 256 + tid;
        int r = slot >> 5, c4 = (slot & 31) << 2;
        float4 wv = *(const float4*)(wbase + (size_t)r * Dh + c4);
        ushort4 pb;
        pb.x = f2bf(wv.x); pb.y = f2bf(wv.y); pb.z = f2bf(wv.z); pb.w = f2bf(wv.w);
        *(ushort4*)&Ws[r * WS_LD + c4] = pb;
    }
    // per-wave: normalized O^T -> Osl[q][d] (b64 writes, q=lrow rows), reread as A-frags [m=q][k=d]
    s16x8 afo[2][4];
    #pragma unroll
    for (int g = 0; g < 2; ++g) {
        float inv = 1.0f / l_run[g];   // per-lane, q = lane&15: no shuffle needed
        #pragma unroll
        for (int nb = 0; nb < 8; ++nb) {
            ushort4 pk;
            pk.x = f2bf(oacc[g][nb][0] * inv);
            pk.y = f2bf(oacc[g][nb][1] * inv);
            pk.z = f2bf(oacc[g][nb][2] * inv);
            pk.w = f2bf(oacc[g][nb][3] * inv);
            *(ushort4*)&Osl[lrow * OS_LD + 16 * nb + quad * 4] = pk;
        }
        #pragma unroll
        for (int kc = 0; kc < 4; ++kc)
            afo[g][kc] = *(const s16x8*)&Osl[lrow * OS_LD + kc * 32 + quad * 8];
    }
    __syncthreads();

    const size_t orow0 = (size_t)b * SS + s0 + 32 * wave;
    #pragma unroll
    for (int nb = 0; nb < 8; ++nb) {
        float bia = bo[h * Dh + nb * 16 + lrow];
        f32x4 facc[2];
        facc[0] = (f32x4){0.f, 0.f, 0.f, 0.f};
        facc[1] = (f32x4){0.f, 0.f, 0.f, 0.f};
        #pragma unroll
        for (int kc = 0; kc < 4; ++kc) {
            s16x8 wf = *(const s16x8*)&Ws[(16 * nb + lrow) * WS_LD + kc * 32 + quad * 8];
            facc[0] = MFMA32(afo[0][kc], wf, facc[0]);
            facc[1] = MFMA32(afo[1][kc], wf, facc[1]);
        }
        #pragma unroll
        for (int g = 0; g < 2; ++g)
            #pragma unroll
            for (int reg = 0; reg < 4; ++reg) {
                size_t m = orow0 + 16 * g + quad * 4 + reg;
                out[m * (NH * Dh) + h * Dh + nb * 16 + lrow] = facc[g][reg] + bia;
            }
    }
}

extern "C" void kernel_launch(void* const* d_in, const int* in_sizes, int n_in,
                              void* d_out, int out_size, void* d_ws, size_t ws_size,
                              hipStream_t stream) {
    const float* x     = (const float*)d_in[0];
    const int*   edge  = (const int*)d_in[1];
    const float* w_in  = (const float*)d_in[2];
    const float* b_in  = (const float*)d_in[3];
    const float* w_out = (const float*)d_in[4];
    const float* b_out = (const float*)d_in[5];
    float* out = (float*)d_out;

    float* ws   = (float*)d_ws;
    float* part = ws;                                              // 512 floats
    unsigned long long* mbit = (unsigned long long*)(ws + 1024);   // [4][1024][16] u64 = 512 KB
    ushort* qo  = (ushort*)(mbit + (size_t)NH * SS * 16);
    const size_t QSZ = (size_t)NB * NH * SS * 128;
    ushort* ko  = qo + QSZ;
    ushort* vto = ko + QSZ;                                        // [b][h][128][s]

    ln_mask_kernel<<<256, 256, 0, stream>>>(x, part, edge, mbit);
    qkv_mfma_kernel<<<dim3(12, 128), 256, 0, stream>>>(x, w_in, b_in, part, qo, ko, vto);
    attn_fused_kernel<<<dim3(NB * NH, SS / 128), 256, 0, stream>>>(qo, ko, vto, mbit, w_out, b_out, out);
}